// Round 8
// baseline (1249.264 us; speedup 1.0000x reference)
//
#include <hip/hip_runtime.h>
#include <hip/hip_fp16.h>

// Problem constants (from reference)
constexpr int N_FRAMES   = 2000;
constexpr int BATCH      = 32;
constexpr int TARGET_LEN = 1000;
constexpr int VOCAB      = 256;
constexpr int RING       = 8;     // emit rows in flight (register ring)
#define NEGF (-1e30f)

// addrspace(1) pointers => guaranteed global_load (vmcnt only, never flat).
// Scalar element types only (HIP vector types can't bind addrspace(1) refs).
typedef __attribute__((address_space(1))) const float* gcfp;
typedef __attribute__((address_space(1))) const unsigned long long* gcu64;

// log2-domain logaddexp cell, emit E already premultiplied by log2(e):
//   dst = E + max(A,U) + log2(1 + 2^(-|A-U|))
#define LSECELL(dst, A, U, E)                                         \
    {                                                                 \
        const float m_ = fmaxf((A), (U));                             \
        const float d_ = (A) - (U);                                   \
        const float x_ = __builtin_amdgcn_exp2f(-fabsf(d_));          \
        const float l_ = __builtin_amdgcn_logf(1.0f + x_);            \
        (dst) = (E) + (m_ + l_);                                      \
    }

#define H2F(us) __half2float(__ushort_as_half((unsigned short)(us)))

// ---------------- Phase 1: massively parallel emit gather ----------------
// emit[b][i][col] = fp16( scores[i,b,tgt[b][min(col,999)]] * log2(e) )
__global__ __launch_bounds__(256)
void gather_emit(const float* __restrict__ scores,
                 const int*   __restrict__ targets,
                 __half*      __restrict__ emit)
{
    constexpr float L2E = 1.44269504088896340736f;
    const int i = blockIdx.x;
    const int b = blockIdx.y;
    const int t = threadIdx.x;

    const gcfp gsc = (gcfp)scores;
    const unsigned sbase = (unsigned)(i * BATCH * VOCAB + b * VOCAB);

    int tk0, tk1, tk2, tk3;
    if (t < TARGET_LEN / 4) {
        const int4 tk = *(const int4*)&targets[b * TARGET_LEN + 4 * t];
        tk0 = tk.x; tk1 = tk.y; tk2 = tk.z; tk3 = tk.w;
    } else {
        tk0 = tk1 = tk2 = tk3 = targets[b * TARGET_LEN + TARGET_LEN - 1];
    }

    const float e0 = gsc[sbase + (unsigned)tk0] * L2E;
    const float e1 = gsc[sbase + (unsigned)tk1] * L2E;
    const float e2 = gsc[sbase + (unsigned)tk2] * L2E;
    const float e3 = gsc[sbase + (unsigned)tk3] * L2E;

    const unsigned long long h0 = __half_as_ushort(__float2half_rn(e0));
    const unsigned long long h1 = __half_as_ushort(__float2half_rn(e1));
    const unsigned long long h2 = __half_as_ushort(__float2half_rn(e2));
    const unsigned long long h3 = __half_as_ushort(__float2half_rn(e3));

    const unsigned long long u = h0 | (h1 << 16) | (h2 << 32) | (h3 << 48);
    *(unsigned long long*)(emit + (((size_t)(b * N_FRAMES + i)) << 10) + 4 * t) = u;
}

// ---------------- Phase 2: barrier-free 4-wave skewed DP ----------------
// Wave w owns cols [256w, 256w+256), 4 cells/lane. Dependency is strictly
// left->right: wave w+1 row i needs only wave w's col (256w+255) of row i-1.
// Handoff via LDS with UNIQUE slot per row (no wraparound -> no lap/ABA ->
// no deadlock): producer writes val THEN seq (volatile; DS ops complete in
// order per wave), consumer reads seq THEN val -- seq==i certifies val.
// Consumer prefetches next row's (seq,val) one row early: zero spin in
// steady state. NO per-row barrier; skew between waves absorbs latency.
__global__ __launch_bounds__(256)
void align_dp_pipe(const __half* __restrict__ emit,   // [B][N][1024] premult
                   const int*    __restrict__ in_len,
                   const int*    __restrict__ tg_len,
                   float*        __restrict__ ws_final)
{
    constexpr float LN2 = 0.69314718055994530942f;

    const int b    = blockIdx.x;
    const int t    = threadIdx.x;
    const int lane = t & 63;
    const int w    = t >> 6;

    __shared__ volatile float    bval[3][N_FRAMES];   // 24 KB
    __shared__ volatile unsigned bseq[3][N_FRAMES];   // 24 KB

    const int inlen = in_len[b];
    const int tlen  = tg_len[b];
    const int fth   = (tlen - 1) >> 2;   // block-thread owning final column
    const int fcc   = (tlen - 1) & 3;

    // u64 index: i*256 + t  (4 packed fp16 per u64; col = 4t..4t+3)
    const gcu64 gem = (gcu64)(emit + (((size_t)b * N_FRAMES) << 10));

    // init seq slots to an impossible row id
    for (int s = t; s < 3 * N_FRAMES; s += 256)
        ((volatile unsigned*)&bseq[0][0])[s] = 0xFFFFFFFFu;
    __syncthreads();   // one-time barrier (init only)

    // ---- row 0: all NEG except global col 0 (value already *L2E in emit) ----
    float p0 = NEGF, p1 = NEGF, p2 = NEGF, p3 = NEGF;
    if (t == 0) p0 = H2F(gem[0] & 0xffffull);
    // publish row-0 boundary (col 256w+255 of row 0 is NEG for every wave)
    if (w < 3 && lane == 63) { bval[w][0] = NEGF; bseq[w][0] = 0u; }

    // ---- emit ring: rows 1..RING in flight (vmcnt-only loads) ----
    unsigned long long ring[RING];
#pragma unroll
    for (int k = 0; k < RING; ++k) ring[k] = gem[((1 + k) << 8) + t];

    // prefetched boundary (seq read BEFORE val read -- certification order)
    unsigned ps = 0xFFFFFFFFu; float pf = NEGF;
    if (w > 0) { ps = bseq[w - 1][0]; pf = bval[w - 1][0]; }

#define STEP(K)                                                                      \
    {                                                                                \
        const int i = ib + (K);                                                      \
        if (i < N_FRAMES) {                                                          \
            float fromL = NEGF;                                                      \
            if (w > 0) {                                                             \
                while (ps != (unsigned)(i - 1)) {                                    \
                    ps = bseq[w - 1][i - 1];   /* seq first */                       \
                    pf = bval[w - 1][i - 1];   /* then val  */                       \
                }                                                                    \
                fromL = pf;                                                          \
            }                                                                        \
            const float sh   = __shfl_up(p3, 1);                                     \
            const float left = (lane == 0) ? fromL : sh;                             \
            const unsigned long long u = ring[K];                                    \
            if (i + RING < N_FRAMES) ring[K] = gem[((i + RING) << 8) + t];           \
            const float e0 = H2F(u);       const float e1 = H2F(u >> 16);            \
            const float e2 = H2F(u >> 32); const float e3 = H2F(u >> 48);            \
            float c0, c1, c2, c3;                                                    \
            LSECELL(c1, p0,   p1, e1);                                               \
            LSECELL(c2, p1,   p2, e2);                                               \
            LSECELL(c3, p2,   p3, e3);                                               \
            LSECELL(c0, left, p0, e0);                                               \
            if (w < 3 && lane == 63) { bval[w][i] = c3; bseq[w][i] = (unsigned)i; }  \
            if (w > 0 && i + 1 < N_FRAMES) {                                         \
                ps = bseq[w - 1][i];           /* prefetch next row's handoff */     \
                pf = bval[w - 1][i];                                                 \
            }                                                                        \
            if (i == inlen - 1 && t == fth) {                                        \
                const float v = (fcc == 0) ? c0 : (fcc == 1) ? c1                    \
                              : (fcc == 2) ? c2 : c3;                                \
                ws_final[b] = v * LN2;                                               \
            }                                                                        \
            p0 = c0; p1 = c1; p2 = c2; p3 = c3;                                      \
        }                                                                            \
    }

    for (int ib = 1; ib < N_FRAMES; ib += RING) {
        STEP(0) STEP(1) STEP(2) STEP(3) STEP(4) STEP(5) STEP(6) STEP(7)
    }
#undef STEP
}

// Final scalar: out = -sum(ws_final)/BATCH. Unconditional write.
__global__ void reduce_kernel(const float* __restrict__ ws_final, float* __restrict__ out)
{
    if (threadIdx.x == 0 && blockIdx.x == 0) {
        float s = 0.0f;
        for (int b = 0; b < BATCH; ++b) s += ws_final[b];
        out[0] = -s / (float)BATCH;
    }
}

// ---------------- Fallback (verified R3 kernel) if ws too small ----------------
#define CELL(dst, A, U, E)                                            \
    {                                                                 \
        const float m_ = fmaxf((A), (U));                             \
        const float d_ = (A) - (U);                                   \
        const float p_ = __builtin_amdgcn_exp2f(-fabsf(d_));          \
        const float l_ = __builtin_amdgcn_logf(1.0f + p_);            \
        (dst) = fmaf((E), L2E, m_ + l_);                              \
    }

__global__ __launch_bounds__(256)
void align_dp4(const float* __restrict__ scores,
               const int*   __restrict__ targets,
               const int*   __restrict__ in_len,
               const int*   __restrict__ tg_len,
               float*       __restrict__ ws_final)
{
    constexpr float L2E = 1.44269504088896340736f;
    constexpr float LN2 = 0.69314718055994530942f;

    const int b    = blockIdx.x;
    const int t    = threadIdx.x;
    const int lane = t & 63;
    const int w    = t >> 6;

    __shared__ float elds[4][VOCAB];
    __shared__ float bnd[2][8];

    const int inlen = in_len[b];
    const int tlen  = tg_len[b];

    const gcfp gsc = (gcfp)scores;
    const unsigned base = (unsigned)(b * VOCAB);
    constexpr unsigned ROWW = (unsigned)(BATCH * VOCAB);

    int tok[4];
#pragma unroll
    for (int c = 0; c < 4; ++c) {
        const int col = t * 4 + c;
        tok[c] = targets[b * TARGET_LEN + (col < TARGET_LEN ? col : TARGET_LEN - 1)];
    }

    float prev[4];
#pragma unroll
    for (int c = 0; c < 4; ++c) prev[c] = NEGF;
    if (t == 0) prev[0] = gsc[base + (unsigned)tok[0]] * L2E;

    elds[1][t] = gsc[1u * ROWW + base + (unsigned)t];
    elds[2][t] = gsc[2u * ROWW + base + (unsigned)t];
    if (lane == 63) bnd[0][w] = NEGF;

    float g[4];
    g[3] = gsc[3u * ROWW + base + (unsigned)t];
    g[0] = gsc[4u * ROWW + base + (unsigned)t];
    g[1] = gsc[5u * ROWW + base + (unsigned)t];
    g[2] = gsc[6u * ROWW + base + (unsigned)t];

    const int fth = (tlen - 1) >> 2;
    const int fcc = (tlen - 1) & 3;

#define STEP(K)                                                                    \
    {                                                                              \
        const int i = ib + (K);                                                    \
        if (i < N_FRAMES) {                                                        \
            asm volatile("s_waitcnt lgkmcnt(0)" ::: "memory");                     \
            __builtin_amdgcn_s_barrier();                                          \
            asm volatile("" ::: "memory");                                         \
            const int sl = i & 3;                                                  \
            const float ec0 = elds[sl][tok[0]];                                    \
            const float ec1 = elds[sl][tok[1]];                                    \
            const float ec2 = elds[sl][tok[2]];                                    \
            const float ec3 = elds[sl][tok[3]];                                    \
            const float fromLds = (w > 0) ? bnd[(i - 1) & 1][w - 1] : NEGF;        \
            if (i + 2 < N_FRAMES) elds[(i + 2) & 3][t] = g[((K) + 3) & 3];         \
            if (i + 6 < N_FRAMES)                                                  \
                g[((K) + 3) & 3] = gsc[(unsigned)(i + 6) * ROWW + base + (unsigned)t]; \
            const float sh   = __shfl_up(prev[3], 1);                              \
            const float left = (lane == 0) ? fromLds : sh;                         \
            float cur0, cur1, cur2, cur3;                                          \
            CELL(cur0, left,    prev[0], ec0);                                     \
            CELL(cur1, prev[0], prev[1], ec1);                                     \
            CELL(cur2, prev[1], prev[2], ec2);                                     \
            CELL(cur3, prev[2], prev[3], ec3);                                     \
            if (lane == 63) bnd[i & 1][w] = cur3;                                  \
            if (i == inlen - 1 && t == fth) {                                      \
                const float v = (fcc == 0) ? cur0 : (fcc == 1) ? cur1              \
                              : (fcc == 2) ? cur2 : cur3;                          \
                ws_final[b] = v * LN2;                                             \
            }                                                                      \
            prev[0] = cur0; prev[1] = cur1; prev[2] = cur2; prev[3] = cur3;        \
        }                                                                          \
    }

    for (int ib = 1; ib < N_FRAMES; ib += 4) {
        STEP(0) STEP(1) STEP(2) STEP(3)
    }
#undef STEP
}

extern "C" void kernel_launch(void* const* d_in, const int* in_sizes, int n_in,
                              void* d_out, int out_size, void* d_ws, size_t ws_size,
                              hipStream_t stream)
{
    const float* scores  = (const float*)d_in[0];
    const int*   targets = (const int*)  d_in[1];
    const int*   in_len  = (const int*)  d_in[2];
    const int*   tg_len  = (const int*)  d_in[3];
    float*       out     = (float*)d_out;
    float*       ws_fin  = (float*)d_ws;                     // [0,256): per-batch finals

    const size_t emit_bytes = (size_t)BATCH * N_FRAMES * 1024 * sizeof(__half);
    const size_t need = 256 + emit_bytes;

    if (ws_size >= need) {
        __half* emit = (__half*)((char*)d_ws + 256);
        dim3 ggrid(N_FRAMES, BATCH);
        gather_emit<<<ggrid, 256, 0, stream>>>(scores, targets, emit);
        align_dp_pipe<<<BATCH, 256, 0, stream>>>(emit, in_len, tg_len, ws_fin);
    } else {
        align_dp4<<<BATCH, 256, 0, stream>>>(scores, targets, in_len, tg_len, ws_fin);
    }
    reduce_kernel<<<1, 64, 0, stream>>>(ws_fin, out);
}

// Round 9
// 935.005 us; speedup vs baseline: 1.3361x; 1.3361x over previous
//
#include <hip/hip_runtime.h>
#include <hip/hip_fp16.h>

// Problem constants (from reference)
constexpr int N_FRAMES   = 2000;
constexpr int BATCH      = 32;
constexpr int TARGET_LEN = 1000;
constexpr int VOCAB      = 256;
constexpr int CH         = 8;                       // rows per handoff chunk
constexpr int NCHUNK     = (N_FRAMES - 1 + CH - 1) / CH;   // 250
#define NEGF (-1e30f)

// addrspace(1) pointers => guaranteed global_load (vmcnt only, never flat).
// Scalar element types only (HIP vector types can't bind addrspace(1) refs).
typedef __attribute__((address_space(1))) const float* gcfp;
typedef __attribute__((address_space(1))) const unsigned long long* gcu64;

// log2-domain logaddexp cell, emit E already premultiplied by log2(e):
//   dst = E + max(A,U) + log2(1 + 2^(-|A-U|))
#define LSECELL(dst, A, U, E)                                         \
    {                                                                 \
        const float m_ = fmaxf((A), (U));                             \
        const float d_ = (A) - (U);                                   \
        const float x_ = __builtin_amdgcn_exp2f(-fabsf(d_));          \
        const float l_ = __builtin_amdgcn_logf(1.0f + x_);            \
        (dst) = (E) + (m_ + l_);                                      \
    }

#define H2F(us) __half2float(__ushort_as_half((unsigned short)(us)))

// ---------------- Phase 1: massively parallel emit gather ----------------
// emit[b][i][col] = fp16( scores[i,b,tgt[b][min(col,999)]] * log2(e) )
__global__ __launch_bounds__(256)
void gather_emit(const float* __restrict__ scores,
                 const int*   __restrict__ targets,
                 __half*      __restrict__ emit)
{
    constexpr float L2E = 1.44269504088896340736f;
    const int i = blockIdx.x;
    const int b = blockIdx.y;
    const int t = threadIdx.x;

    const gcfp gsc = (gcfp)scores;
    const unsigned sbase = (unsigned)(i * BATCH * VOCAB + b * VOCAB);

    int tk0, tk1, tk2, tk3;
    if (t < TARGET_LEN / 4) {
        const int4 tk = *(const int4*)&targets[b * TARGET_LEN + 4 * t];
        tk0 = tk.x; tk1 = tk.y; tk2 = tk.z; tk3 = tk.w;
    } else {
        tk0 = tk1 = tk2 = tk3 = targets[b * TARGET_LEN + TARGET_LEN - 1];
    }

    const float e0 = gsc[sbase + (unsigned)tk0] * L2E;
    const float e1 = gsc[sbase + (unsigned)tk1] * L2E;
    const float e2 = gsc[sbase + (unsigned)tk2] * L2E;
    const float e3 = gsc[sbase + (unsigned)tk3] * L2E;

    const unsigned long long h0 = __half_as_ushort(__float2half_rn(e0));
    const unsigned long long h1 = __half_as_ushort(__float2half_rn(e1));
    const unsigned long long h2 = __half_as_ushort(__float2half_rn(e2));
    const unsigned long long h3 = __half_as_ushort(__float2half_rn(e3));

    const unsigned long long u = h0 | (h1 << 16) | (h2 << 32) | (h3 << 48);
    *(unsigned long long*)(emit + (((size_t)(b * N_FRAMES + i)) << 10) + 4 * t) = u;
}

// ---------------- Phase 2: 4-wave skewed DP, CHUNKED handoff ----------------
// Wave w owns cols [256w, 256w+256), 4 cells/lane. Handoff of the boundary
// column happens once per CH=8 rows: producer lane63 accumulates 8 c3 values
// in registers, writes them + a seq flag (unique slot per chunk -> no ABA, no
// deadlock); consumer spins once per chunk then reads all 8 behind one wait.
// Per-row hot path has NO volatile LDS ops and NO barriers.
__global__ __launch_bounds__(256)
void align_dp_chunk(const __half* __restrict__ emit,   // [B][N][1024] premult
                    const int*    __restrict__ in_len,
                    const int*    __restrict__ tg_len,
                    float*        __restrict__ ws_final)
{
    constexpr float LN2 = 0.69314718055994530942f;

    const int b    = blockIdx.x;
    const int t    = threadIdx.x;
    const int lane = t & 63;
    const int w    = t >> 6;

    __shared__ float    bval[3][NCHUNK][CH];   // 24 KB
    __shared__ unsigned bseq[3][NCHUNK];       //  3 KB

    // one-time init of seq flags
    for (int s = t; s < 3 * NCHUNK; s += 256)
        (&bseq[0][0])[s] = 0xFFFFFFFFu;
    __syncthreads();

    const int inlen = in_len[b];
    const int tlen  = tg_len[b];
    const int fth   = (tlen - 1) >> 2;   // block-thread owning final column
    const int fcc   = (tlen - 1) & 3;

    // u64 index: i*256 + t  (4 packed fp16 per u64; col = 4t..4t+3)
    const gcu64 gem = (gcu64)(emit + (((size_t)b * N_FRAMES) << 10));

    // ---- row 0: all NEG except global col 0 (value already *L2E) ----
    float p0 = NEGF, p1 = NEGF, p2 = NEGF, p3 = NEGF;
    if (t == 0) p0 = H2F(gem[0] & 0xffffull);

    // ---- emit ring: rows 1..CH in flight; slot r holds row i0+r ----
    unsigned long long ring[CH];
#pragma unroll
    for (int r = 0; r < CH; ++r) ring[r] = gem[((1 + r) << 8) + t];

    float carry = NEGF;   // producer boundary of row i0-1 (last row of prev chunk)
    const volatile unsigned* seqp = (w > 0) ? &bseq[w - 1][0] : (const volatile unsigned*)nullptr;

    // One row of the DP. c3/c2 first (cross-row chain), c0 last (shfl consumer).
#define ROW(r, Bv, Ov)                                                          \
    {                                                                           \
        const int i = i0 + (r);                                                 \
        if (i < N_FRAMES) {                                                     \
            const float sh   = __shfl_up(p3, 1);                                \
            const unsigned long long u = ring[r];                               \
            if (i + CH < N_FRAMES) ring[r] = gem[((i + CH) << 8) + t];          \
            const float e0 = H2F(u);       const float e1 = H2F(u >> 16);       \
            const float e2 = H2F(u >> 32); const float e3 = H2F(u >> 48);       \
            float c0, c1, c2, c3;                                               \
            LSECELL(c3, p2, p3, e3);                                            \
            LSECELL(c2, p1, p2, e2);                                            \
            LSECELL(c1, p0, p1, e1);                                            \
            const float left = (lane == 0) ? (Bv) : sh;                         \
            LSECELL(c0, left, p0, e0);                                          \
            (Ov) = c3;                                                          \
            if (i == inlen - 1 && t == fth) {                                   \
                const float v = (fcc == 0) ? c0 : (fcc == 1) ? c1               \
                              : (fcc == 2) ? c2 : c3;                           \
                ws_final[b] = v * LN2;                                          \
            }                                                                   \
            p0 = c0; p1 = c1; p2 = c2; p3 = c3;                                 \
        } else { (Ov) = NEGF; }                                                 \
    }

    for (int c = 0; c < NCHUNK; ++c) {
        const int i0 = 1 + c * CH;

        // ---- consumer: one spin + 8 broadcast reads per chunk ----
        float B0 = NEGF, B1 = NEGF, B2 = NEGF, B3 = NEGF,
              B4 = NEGF, B5 = NEGF, B6 = NEGF, B7 = NEGF;
        if (w > 0) {
            unsigned s;
            do { s = seqp[c]; } while (s != (unsigned)c);
            asm volatile("" ::: "memory");    // pin val reads after spin exit
            const float* vp = &bval[w - 1][c][0];
            B0 = carry;
            B1 = vp[0]; B2 = vp[1]; B3 = vp[2]; B4 = vp[3];
            B5 = vp[4]; B6 = vp[5]; B7 = vp[6];
            carry = vp[7];
        }

        float o0, o1, o2, o3, o4, o5, o6, o7;
        ROW(0, B0, o0) ROW(1, B1, o1) ROW(2, B2, o2) ROW(3, B3, o3)
        ROW(4, B4, o4) ROW(5, B5, o5) ROW(6, B6, o6) ROW(7, B7, o7)

        // ---- producer: burst-publish 8 boundary values + seq flag ----
        if (w < 3) {
            if (lane == 63) {
                float* dp = &bval[w][c][0];
                dp[0] = o0; dp[1] = o1; dp[2] = o2; dp[3] = o3;
                dp[4] = o4; dp[5] = o5; dp[6] = o6; dp[7] = o7;
            }
            asm volatile("s_waitcnt lgkmcnt(0)" ::: "memory");  // vals visible...
            if (lane == 63) bseq[w][c] = (unsigned)c;           // ...before seq
        }
    }
#undef ROW
}

// Final scalar: out = -sum(ws_final)/BATCH. Unconditional write.
__global__ void reduce_kernel(const float* __restrict__ ws_final, float* __restrict__ out)
{
    if (threadIdx.x == 0 && blockIdx.x == 0) {
        float s = 0.0f;
        for (int b = 0; b < BATCH; ++b) s += ws_final[b];
        out[0] = -s / (float)BATCH;
    }
}

// ---------------- Fallback (verified R3 kernel) if ws too small ----------------
#define CELL(dst, A, U, E)                                            \
    {                                                                 \
        const float m_ = fmaxf((A), (U));                             \
        const float d_ = (A) - (U);                                   \
        const float p_ = __builtin_amdgcn_exp2f(-fabsf(d_));          \
        const float l_ = __builtin_amdgcn_logf(1.0f + p_);            \
        (dst) = fmaf((E), L2E, m_ + l_);                              \
    }

__global__ __launch_bounds__(256)
void align_dp4(const float* __restrict__ scores,
               const int*   __restrict__ targets,
               const int*   __restrict__ in_len,
               const int*   __restrict__ tg_len,
               float*       __restrict__ ws_final)
{
    constexpr float L2E = 1.44269504088896340736f;
    constexpr float LN2 = 0.69314718055994530942f;

    const int b    = blockIdx.x;
    const int t    = threadIdx.x;
    const int lane = t & 63;
    const int w    = t >> 6;

    __shared__ float elds[4][VOCAB];
    __shared__ float bnd[2][8];

    const int inlen = in_len[b];
    const int tlen  = tg_len[b];

    const gcfp gsc = (gcfp)scores;
    const unsigned base = (unsigned)(b * VOCAB);
    constexpr unsigned ROWW = (unsigned)(BATCH * VOCAB);

    int tok[4];
#pragma unroll
    for (int c = 0; c < 4; ++c) {
        const int col = t * 4 + c;
        tok[c] = targets[b * TARGET_LEN + (col < TARGET_LEN ? col : TARGET_LEN - 1)];
    }

    float prev[4];
#pragma unroll
    for (int c = 0; c < 4; ++c) prev[c] = NEGF;
    if (t == 0) prev[0] = gsc[base + (unsigned)tok[0]] * L2E;

    elds[1][t] = gsc[1u * ROWW + base + (unsigned)t];
    elds[2][t] = gsc[2u * ROWW + base + (unsigned)t];
    if (lane == 63) bnd[0][w] = NEGF;

    float g[4];
    g[3] = gsc[3u * ROWW + base + (unsigned)t];
    g[0] = gsc[4u * ROWW + base + (unsigned)t];
    g[1] = gsc[5u * ROWW + base + (unsigned)t];
    g[2] = gsc[6u * ROWW + base + (unsigned)t];

    const int fth = (tlen - 1) >> 2;
    const int fcc = (tlen - 1) & 3;

#define STEP(K)                                                                    \
    {                                                                              \
        const int i = ib + (K);                                                    \
        if (i < N_FRAMES) {                                                        \
            asm volatile("s_waitcnt lgkmcnt(0)" ::: "memory");                     \
            __builtin_amdgcn_s_barrier();                                          \
            asm volatile("" ::: "memory");                                         \
            const int sl = i & 3;                                                  \
            const float ec0 = elds[sl][tok[0]];                                    \
            const float ec1 = elds[sl][tok[1]];                                    \
            const float ec2 = elds[sl][tok[2]];                                    \
            const float ec3 = elds[sl][tok[3]];                                    \
            const float fromLds = (w > 0) ? bnd[(i - 1) & 1][w - 1] : NEGF;        \
            if (i + 2 < N_FRAMES) elds[(i + 2) & 3][t] = g[((K) + 3) & 3];         \
            if (i + 6 < N_FRAMES)                                                  \
                g[((K) + 3) & 3] = gsc[(unsigned)(i + 6) * ROWW + base + (unsigned)t]; \
            const float sh   = __shfl_up(prev[3], 1);                              \
            const float left = (lane == 0) ? fromLds : sh;                         \
            float cur0, cur1, cur2, cur3;                                          \
            CELL(cur0, left,    prev[0], ec0);                                     \
            CELL(cur1, prev[0], prev[1], ec1);                                     \
            CELL(cur2, prev[1], prev[2], ec2);                                     \
            CELL(cur3, prev[2], prev[3], ec3);                                     \
            if (lane == 63) bnd[i & 1][w] = cur3;                                  \
            if (i == inlen - 1 && t == fth) {                                      \
                const float v = (fcc == 0) ? cur0 : (fcc == 1) ? cur1              \
                              : (fcc == 2) ? cur2 : cur3;                          \
                ws_final[b] = v * LN2;                                             \
            }                                                                      \
            prev[0] = cur0; prev[1] = cur1; prev[2] = cur2; prev[3] = cur3;        \
        }                                                                          \
    }

    for (int ib = 1; ib < N_FRAMES; ib += 4) {
        STEP(0) STEP(1) STEP(2) STEP(3)
    }
#undef STEP
}

extern "C" void kernel_launch(void* const* d_in, const int* in_sizes, int n_in,
                              void* d_out, int out_size, void* d_ws, size_t ws_size,
                              hipStream_t stream)
{
    const float* scores  = (const float*)d_in[0];
    const int*   targets = (const int*)  d_in[1];
    const int*   in_len  = (const int*)  d_in[2];
    const int*   tg_len  = (const int*)  d_in[3];
    float*       out     = (float*)d_out;
    float*       ws_fin  = (float*)d_ws;                     // [0,256): per-batch finals

    const size_t emit_bytes = (size_t)BATCH * N_FRAMES * 1024 * sizeof(__half);
    const size_t need = 256 + emit_bytes;

    if (ws_size >= need) {
        __half* emit = (__half*)((char*)d_ws + 256);
        dim3 ggrid(N_FRAMES, BATCH);
        gather_emit<<<ggrid, 256, 0, stream>>>(scores, targets, emit);
        align_dp_chunk<<<BATCH, 256, 0, stream>>>(emit, in_len, tg_len, ws_fin);
    } else {
        align_dp4<<<BATCH, 256, 0, stream>>>(scores, targets, in_len, tg_len, ws_fin);
    }
    reduce_kernel<<<1, 64, 0, stream>>>(ws_fin, out);
}

// Round 10
// 568.240 us; speedup vs baseline: 2.1985x; 1.6454x over previous
//
#include <hip/hip_runtime.h>
#include <hip/hip_fp16.h>

// Problem constants (from reference)
constexpr int N_FRAMES   = 2000;
constexpr int BATCH      = 32;
constexpr int TARGET_LEN = 1000;
constexpr int VOCAB      = 256;
constexpr int CH         = 16;                              // rows per chunk/phase
constexpr int NCH        = (N_FRAMES - 1 + CH - 1) / CH;    // 125 chunks over rows 1..1999
#define NEGF (-1e30f)

// addrspace(1) pointers => guaranteed global_load (vmcnt only, never flat).
// Scalar element types only (HIP vector types can't bind addrspace(1) refs).
typedef __attribute__((address_space(1))) const float* gcfp;
typedef __attribute__((address_space(1))) const unsigned long long* gcu64;

// log2(1+x) on [0,1] via degree-5 minimax (A&S 4.1.44 * log2e), |err|<=1.5e-5.
// Replaces v_log_f32 (trans, ~16cy) + add with 4 FMA + 1 mul (~10cy).
__device__ __forceinline__ float log2_1p(float x) {
    float t = fmaf(x, 0.0464048f, -0.1963066f);
    t = fmaf(x, t, 0.4176245f);
    t = fmaf(x, t, -0.7096745f);
    t = fmaf(x, t, 1.44196727f);
    return x * t;
}

// log2-domain logaddexp cell, emit E already premultiplied by log2(e):
//   dst = E + max(A,U) + log2(1 + 2^(-|A-U|))    [single trans: exp2]
#define LSECELL(dst, A, U, E)                                         \
    {                                                                 \
        const float m_ = fmaxf((A), (U));                             \
        const float d_ = (A) - (U);                                   \
        const float x_ = __builtin_amdgcn_exp2f(-fabsf(d_));          \
        (dst) = (E) + (m_ + log2_1p(x_));                             \
    }

#define H2F(us) __half2float(__ushort_as_half((unsigned short)(us)))

// ---------------- Phase 1: massively parallel emit gather ----------------
// emit[b][i][col] = fp16( scores[i,b,tgt[b][min(col,999)]] * log2(e) )
__global__ __launch_bounds__(256)
void gather_emit(const float* __restrict__ scores,
                 const int*   __restrict__ targets,
                 __half*      __restrict__ emit)
{
    constexpr float L2E = 1.44269504088896340736f;
    const int i = blockIdx.x;
    const int b = blockIdx.y;
    const int t = threadIdx.x;

    const gcfp gsc = (gcfp)scores;
    const unsigned sbase = (unsigned)(i * BATCH * VOCAB + b * VOCAB);

    int tk0, tk1, tk2, tk3;
    if (t < TARGET_LEN / 4) {
        const int4 tk = *(const int4*)&targets[b * TARGET_LEN + 4 * t];
        tk0 = tk.x; tk1 = tk.y; tk2 = tk.z; tk3 = tk.w;
    } else {
        tk0 = tk1 = tk2 = tk3 = targets[b * TARGET_LEN + TARGET_LEN - 1];
    }

    const float e0 = gsc[sbase + (unsigned)tk0] * L2E;
    const float e1 = gsc[sbase + (unsigned)tk1] * L2E;
    const float e2 = gsc[sbase + (unsigned)tk2] * L2E;
    const float e3 = gsc[sbase + (unsigned)tk3] * L2E;

    const unsigned long long h0 = __half_as_ushort(__float2half_rn(e0));
    const unsigned long long h1 = __half_as_ushort(__float2half_rn(e1));
    const unsigned long long h2 = __half_as_ushort(__float2half_rn(e2));
    const unsigned long long h3 = __half_as_ushort(__float2half_rn(e3));

    const unsigned long long u = h0 | (h1 << 16) | (h2 << 32) | (h3 << 48);
    *(unsigned long long*)(emit + (((size_t)(b * N_FRAMES + i)) << 10) + 4 * t) = u;
}

// ---------------- Phase 2: 2-wave software-pipelined DP ----------------
// Wave 0: cols [0,512), wave 1: cols [512,1024), 8 cells/lane.
// Phase p: wave 0 computes chunk p (rows 1+16p .. 16+16p) and publishes its 16
// boundary (col 511) values to bpub[p&1]; wave 1 computes chunk p-1 reading
// bpub[(p-1)&1]. One raw s_barrier per phase (lgkmcnt-only drain before it;
// the emit-ring vmcnt loads survive). No spin, no volatile, no per-row sync.
__global__ __launch_bounds__(128)
void align_dp_2w(const __half* __restrict__ emit,   // [B][N][1024] premult
                 const int*    __restrict__ in_len,
                 const int*    __restrict__ tg_len,
                 float*        __restrict__ ws_final)
{
    constexpr float LN2 = 0.69314718055994530942f;

    const int b    = blockIdx.x;
    const int t    = threadIdx.x;
    const int lane = t & 63;
    const int w    = t >> 6;

    __shared__ float bpub[2][CH];   // wave-0 boundary values, phase-parity dbuf

    const int inlen = in_len[b];
    const int tlen  = tg_len[b];
    const int fth   = (tlen - 1) >> 3;   // block-thread owning final column
    const int fcc   = (tlen - 1) & 7;

    // u64 index: i*256 + WB + 2*lane + q   (4 packed fp16 per u64)
    const gcu64 gem = (gcu64)(emit + (((size_t)b * N_FRAMES) << 10));
    const unsigned WB = (w == 1) ? 128u : 0u;

    // ---- row 0: all NEG except global col 0 (value already *L2E) ----
    float p0 = NEGF, p1 = NEGF, p2 = NEGF, p3 = NEGF,
          p4 = NEGF, p5 = NEGF, p6 = NEGF, p7 = NEGF;
    if (t == 0) p0 = H2F(gem[0] & 0xffffull);

    // ---- emit ring: CH rows x 2 u64 in flight (vmcnt-only loads) ----
    // Wave 1 runs one chunk behind: preload ITS first chunk (same rows 1..16,
    // consumed at phase 1). Refill inside ROW uses each wave's own row index.
    unsigned long long ring[CH][2];
#pragma unroll
    for (int r = 0; r < CH; ++r) {
        ring[r][0] = gem[(unsigned)((1 + r) << 8) + WB + (unsigned)(lane << 1)];
        ring[r][1] = gem[(unsigned)((1 + r) << 8) + WB + (unsigned)(lane << 1) + 1u];
    }

    float carry = NEGF;   // consumer: boundary of the row preceding its chunk

    // One DP row. LEFTV = value for lane0's left input; OUT = boundary (c7).
#define ROW(r, LEFTV, OUT)                                                       \
    {                                                                            \
        const int i = i0 + (r);                                                  \
        if (i < N_FRAMES) {                                                      \
            const float sh = __shfl_up(p7, 1);                                   \
            const unsigned long long u0 = ring[r][0];                            \
            const unsigned long long u1 = ring[r][1];                            \
            if (i + CH < N_FRAMES) {                                             \
                ring[r][0] = gem[(unsigned)((i + CH) << 8) + WB + (unsigned)(lane << 1)];      \
                ring[r][1] = gem[(unsigned)((i + CH) << 8) + WB + (unsigned)(lane << 1) + 1u]; \
            }                                                                    \
            const float e0 = H2F(u0);       const float e1 = H2F(u0 >> 16);      \
            const float e2 = H2F(u0 >> 32); const float e3 = H2F(u0 >> 48);      \
            const float e4 = H2F(u1);       const float e5 = H2F(u1 >> 16);      \
            const float e6 = H2F(u1 >> 32); const float e7 = H2F(u1 >> 48);      \
            float c0, c1, c2, c3, c4, c5, c6, c7;                                \
            LSECELL(c7, p6, p7, e7); LSECELL(c6, p5, p6, e6);                    \
            LSECELL(c5, p4, p5, e5); LSECELL(c4, p3, p4, e4);                    \
            LSECELL(c3, p2, p3, e3); LSECELL(c2, p1, p2, e2);                    \
            LSECELL(c1, p0, p1, e1);                                             \
            const float left = (lane == 0) ? (LEFTV) : sh;                       \
            LSECELL(c0, left, p0, e0);                                           \
            (OUT) = c7;                                                          \
            if (i == inlen - 1 && t == fth) {                                    \
                float v_ = c0;                                                   \
                if (fcc == 1) v_ = c1; if (fcc == 2) v_ = c2;                    \
                if (fcc == 3) v_ = c3; if (fcc == 4) v_ = c4;                    \
                if (fcc == 5) v_ = c5; if (fcc == 6) v_ = c6;                    \
                if (fcc == 7) v_ = c7;                                           \
                ws_final[b] = v_ * LN2;                                          \
            }                                                                    \
            p0 = c0; p1 = c1; p2 = c2; p3 = c3;                                  \
            p4 = c4; p5 = c5; p6 = c6; p7 = c7;                                  \
        } else { (OUT) = NEGF; }                                                 \
    }

    for (int p = 0; p <= NCH; ++p) {
        if (w == 0) {
            if (p < NCH) {
                const int i0 = 1 + p * CH;
                const int sl = p & 1;
                float o;
                // producer rows: lane0 left edge is the global edge (NEGF);
                // publish lane63's c7 per row to bpub[sl][r].
#define PROW(r) { ROW(r, NEGF, o); if (lane == 63) bpub[sl][r] = o; }
                PROW(0)  PROW(1)  PROW(2)  PROW(3)
                PROW(4)  PROW(5)  PROW(6)  PROW(7)
                PROW(8)  PROW(9)  PROW(10) PROW(11)
                PROW(12) PROW(13) PROW(14) PROW(15)
#undef PROW
            }
        } else {
            if (p >= 1) {
                const int i0 = 1 + (p - 1) * CH;
                const int sl = (p - 1) & 1;
                // consumer: boundary of rows i0-1 .. i0+14 = carry, bpub[0..14]
                const float B0  = carry;
                const float B1  = bpub[sl][0];  const float B2  = bpub[sl][1];
                const float B3  = bpub[sl][2];  const float B4  = bpub[sl][3];
                const float B5  = bpub[sl][4];  const float B6  = bpub[sl][5];
                const float B7  = bpub[sl][6];  const float B8  = bpub[sl][7];
                const float B9  = bpub[sl][8];  const float B10 = bpub[sl][9];
                const float B11 = bpub[sl][10]; const float B12 = bpub[sl][11];
                const float B13 = bpub[sl][12]; const float B14 = bpub[sl][13];
                const float B15 = bpub[sl][14];
                carry = bpub[sl][15];
                float dummy;
#define CROW(r, Bv) ROW(r, Bv, dummy)
                CROW(0, B0)   CROW(1, B1)   CROW(2, B2)   CROW(3, B3)
                CROW(4, B4)   CROW(5, B5)   CROW(6, B6)   CROW(7, B7)
                CROW(8, B8)   CROW(9, B9)   CROW(10, B10) CROW(11, B11)
                CROW(12, B12) CROW(13, B13) CROW(14, B14) CROW(15, B15)
#undef CROW
            }
        }
        // producer's ds_writes (and consumer's reads) retired before rendezvous;
        // raw barrier: vmcnt emit-ring loads stay in flight.
        asm volatile("s_waitcnt lgkmcnt(0)" ::: "memory");
        __builtin_amdgcn_s_barrier();
        asm volatile("" ::: "memory");
    }
#undef ROW
}

// Final scalar: out = -sum(ws_final)/BATCH. Unconditional write.
__global__ void reduce_kernel(const float* __restrict__ ws_final, float* __restrict__ out)
{
    if (threadIdx.x == 0 && blockIdx.x == 0) {
        float s = 0.0f;
        for (int b = 0; b < BATCH; ++b) s += ws_final[b];
        out[0] = -s / (float)BATCH;
    }
}

// ---------------- Fallback (verified R3 kernel) if ws too small ----------------
#define CELL(dst, A, U, E)                                            \
    {                                                                 \
        const float m_ = fmaxf((A), (U));                             \
        const float d_ = (A) - (U);                                   \
        const float p_ = __builtin_amdgcn_exp2f(-fabsf(d_));          \
        const float l_ = __builtin_amdgcn_logf(1.0f + p_);            \
        (dst) = fmaf((E), L2E, m_ + l_);                              \
    }

__global__ __launch_bounds__(256)
void align_dp4(const float* __restrict__ scores,
               const int*   __restrict__ targets,
               const int*   __restrict__ in_len,
               const int*   __restrict__ tg_len,
               float*       __restrict__ ws_final)
{
    constexpr float L2E = 1.44269504088896340736f;
    constexpr float LN2 = 0.69314718055994530942f;

    const int b    = blockIdx.x;
    const int t    = threadIdx.x;
    const int lane = t & 63;
    const int w    = t >> 6;

    __shared__ float elds[4][VOCAB];
    __shared__ float bnd[2][8];

    const int inlen = in_len[b];
    const int tlen  = tg_len[b];

    const gcfp gsc = (gcfp)scores;
    const unsigned base = (unsigned)(b * VOCAB);
    constexpr unsigned ROWW = (unsigned)(BATCH * VOCAB);

    int tok[4];
#pragma unroll
    for (int c = 0; c < 4; ++c) {
        const int col = t * 4 + c;
        tok[c] = targets[b * TARGET_LEN + (col < TARGET_LEN ? col : TARGET_LEN - 1)];
    }

    float prev[4];
#pragma unroll
    for (int c = 0; c < 4; ++c) prev[c] = NEGF;
    if (t == 0) prev[0] = gsc[base + (unsigned)tok[0]] * L2E;

    elds[1][t] = gsc[1u * ROWW + base + (unsigned)t];
    elds[2][t] = gsc[2u * ROWW + base + (unsigned)t];
    if (lane == 63) bnd[0][w] = NEGF;

    float g[4];
    g[3] = gsc[3u * ROWW + base + (unsigned)t];
    g[0] = gsc[4u * ROWW + base + (unsigned)t];
    g[1] = gsc[5u * ROWW + base + (unsigned)t];
    g[2] = gsc[6u * ROWW + base + (unsigned)t];

    const int fth = (tlen - 1) >> 2;
    const int fcc = (tlen - 1) & 3;

#define STEP(K)                                                                    \
    {                                                                              \
        const int i = ib + (K);                                                    \
        if (i < N_FRAMES) {                                                        \
            asm volatile("s_waitcnt lgkmcnt(0)" ::: "memory");                     \
            __builtin_amdgcn_s_barrier();                                          \
            asm volatile("" ::: "memory");                                         \
            const int sl = i & 3;                                                  \
            const float ec0 = elds[sl][tok[0]];                                    \
            const float ec1 = elds[sl][tok[1]];                                    \
            const float ec2 = elds[sl][tok[2]];                                    \
            const float ec3 = elds[sl][tok[3]];                                    \
            const float fromLds = (w > 0) ? bnd[(i - 1) & 1][w - 1] : NEGF;        \
            if (i + 2 < N_FRAMES) elds[(i + 2) & 3][t] = g[((K) + 3) & 3];         \
            if (i + 6 < N_FRAMES)                                                  \
                g[((K) + 3) & 3] = gsc[(unsigned)(i + 6) * ROWW + base + (unsigned)t]; \
            const float sh   = __shfl_up(prev[3], 1);                              \
            const float left = (lane == 0) ? fromLds : sh;                         \
            float cur0, cur1, cur2, cur3;                                          \
            CELL(cur0, left,    prev[0], ec0);                                     \
            CELL(cur1, prev[0], prev[1], ec1);                                     \
            CELL(cur2, prev[1], prev[2], ec2);                                     \
            CELL(cur3, prev[2], prev[3], ec3);                                     \
            if (lane == 63) bnd[i & 1][w] = cur3;                                  \
            if (i == inlen - 1 && t == fth) {                                      \
                const float v = (fcc == 0) ? cur0 : (fcc == 1) ? cur1              \
                              : (fcc == 2) ? cur2 : cur3;                          \
                ws_final[b] = v * LN2;                                             \
            }                                                                      \
            prev[0] = cur0; prev[1] = cur1; prev[2] = cur2; prev[3] = cur3;        \
        }                                                                          \
    }

    for (int ib = 1; ib < N_FRAMES; ib += 4) {
        STEP(0) STEP(1) STEP(2) STEP(3)
    }
#undef STEP
}

extern "C" void kernel_launch(void* const* d_in, const int* in_sizes, int n_in,
                              void* d_out, int out_size, void* d_ws, size_t ws_size,
                              hipStream_t stream)
{
    const float* scores  = (const float*)d_in[0];
    const int*   targets = (const int*)  d_in[1];
    const int*   in_len  = (const int*)  d_in[2];
    const int*   tg_len  = (const int*)  d_in[3];
    float*       out     = (float*)d_out;
    float*       ws_fin  = (float*)d_ws;                     // [0,256): per-batch finals

    const size_t emit_bytes = (size_t)BATCH * N_FRAMES * 1024 * sizeof(__half);
    const size_t need = 256 + emit_bytes;

    if (ws_size >= need) {
        __half* emit = (__half*)((char*)d_ws + 256);
        dim3 ggrid(N_FRAMES, BATCH);
        gather_emit<<<ggrid, 256, 0, stream>>>(scores, targets, emit);
        align_dp_2w<<<BATCH, 128, 0, stream>>>(emit, in_len, tg_len, ws_fin);
    } else {
        align_dp4<<<BATCH, 256, 0, stream>>>(scores, targets, in_len, tg_len, ws_fin);
    }
    reduce_kernel<<<1, 64, 0, stream>>>(ws_fin, out);
}

// Round 11
// 365.265 us; speedup vs baseline: 3.4202x; 1.5557x over previous
//
#include <hip/hip_runtime.h>
#include <hip/hip_fp16.h>

// Problem constants (from reference)
constexpr int N_FRAMES   = 2000;
constexpr int BATCH      = 32;
constexpr int TARGET_LEN = 1000;
constexpr int VOCAB      = 256;
constexpr int CH         = 16;                              // rows per chunk/phase
constexpr int NCH        = (N_FRAMES - 1 + CH - 1) / CH;    // 125
constexpr int NPH        = NCH + 3;                         // 128 phases (4-wave skew)
#define NEGF (-1e30f)

// addrspace(1) pointers => guaranteed global_load (vmcnt only, never flat).
// Scalar element types only (HIP vector types can't bind addrspace(1) refs).
typedef __attribute__((address_space(1))) const float* gcfp;
typedef __attribute__((address_space(1))) const unsigned long long* gcu64;

// log2(1+x) on [0,1], degree-5 minimax, |err|<=1.6e-5 (validated R9, absmax 0.0)
__device__ __forceinline__ float log2_1p(float x) {
    float t = fmaf(x, 0.0464048f, -0.1963066f);
    t = fmaf(x, t, 0.4176245f);
    t = fmaf(x, t, -0.7096745f);
    t = fmaf(x, t, 1.44196727f);
    return x * t;
}

// log2-domain logaddexp cell, emit E already premultiplied by log2(e):
//   dst = E + max(A,U) + log2(1 + 2^(-|A-U|))    [single trans: exp2]
#define LSECELL(dst, A, U, E)                                         \
    {                                                                 \
        const float m_ = fmaxf((A), (U));                             \
        const float d_ = (A) - (U);                                   \
        const float x_ = __builtin_amdgcn_exp2f(-fabsf(d_));          \
        (dst) = (E) + (m_ + log2_1p(x_));                             \
    }

#define H2F(us) __half2float(__ushort_as_half((unsigned short)(us)))

// ---------------- Phase 1: massively parallel emit gather ----------------
// emit[b][i][col] = fp16( scores[i,b,tgt[b][min(col,999)]] * log2(e) )
__global__ __launch_bounds__(256)
void gather_emit(const float* __restrict__ scores,
                 const int*   __restrict__ targets,
                 __half*      __restrict__ emit)
{
    constexpr float L2E = 1.44269504088896340736f;
    const int i = blockIdx.x;
    const int b = blockIdx.y;
    const int t = threadIdx.x;

    const gcfp gsc = (gcfp)scores;
    const unsigned sbase = (unsigned)(i * BATCH * VOCAB + b * VOCAB);

    int tk0, tk1, tk2, tk3;
    if (t < TARGET_LEN / 4) {
        const int4 tk = *(const int4*)&targets[b * TARGET_LEN + 4 * t];
        tk0 = tk.x; tk1 = tk.y; tk2 = tk.z; tk3 = tk.w;
    } else {
        tk0 = tk1 = tk2 = tk3 = targets[b * TARGET_LEN + TARGET_LEN - 1];
    }

    const float e0 = gsc[sbase + (unsigned)tk0] * L2E;
    const float e1 = gsc[sbase + (unsigned)tk1] * L2E;
    const float e2 = gsc[sbase + (unsigned)tk2] * L2E;
    const float e3 = gsc[sbase + (unsigned)tk3] * L2E;

    const unsigned long long h0 = __half_as_ushort(__float2half_rn(e0));
    const unsigned long long h1 = __half_as_ushort(__float2half_rn(e1));
    const unsigned long long h2 = __half_as_ushort(__float2half_rn(e2));
    const unsigned long long h3 = __half_as_ushort(__float2half_rn(e3));

    const unsigned long long u = h0 | (h1 << 16) | (h2 << 32) | (h3 << 48);
    *(unsigned long long*)(emit + (((size_t)(b * N_FRAMES + i)) << 10) + 4 * t) = u;
}

// ---------------- Phase 2: 4-wave skewed software-pipelined DP ----------------
// Wave w owns cols [256w, 256(w+1)), 4 cells/lane (col = 4t + c).
// Phase p: wave w computes chunk q=p-w (rows 1+16q .. 16+16q). Boundary column
// handoff wave w -> w+1 via bpub[w][q&1][16]; one raw s_barrier per phase
// (lgkmcnt-only drain; emit-ring vmcnt loads survive). Hot chunk bodies are
// BRANCHLESS straight-line code (store-check / tail-guard folded by constant
// bools); shfl for row i+1 issued right after row i's boundary cell.
__global__ __launch_bounds__(256)
void align_dp_4w(const __half* __restrict__ emit,   // [B][N][1024] premult
                 const int*    __restrict__ in_len,
                 const int*    __restrict__ tg_len,
                 float*        __restrict__ ws_final)
{
    constexpr float LN2 = 0.69314718055994530942f;

    const int b    = blockIdx.x;
    const int t    = threadIdx.x;
    const int lane = t & 63;
    const int w    = t >> 6;
    const bool wlt3 = (w < 3);

    __shared__ float bpub[3][2][CH];   // boundary handoff, chunk-parity dbuf (384B)

    const int inlen = in_len[b];
    const int tlen  = tg_len[b];
    const int fth   = (tlen - 1) >> 2;   // block-thread owning final column
    const int fcc   = (tlen - 1) & 3;

    // u64 index: i*256 + t   (4 packed fp16 per u64; cols 4t..4t+3)
    const gcu64 gem = (gcu64)(emit + (((size_t)b * N_FRAMES) << 10));

    // ---- row 0: all NEG except global col 0 (value already *L2E) ----
    float p0 = NEGF, p1 = NEGF, p2 = NEGF, p3 = NEGF;
    if (t == 0) p0 = H2F(gem[0] & 0xffffull);

    // ---- emit ring: 16 rows in flight; slot r holds row (1+16q)+r ----
    unsigned long long ring[CH];
#pragma unroll
    for (int r = 0; r < CH; ++r) ring[r] = gem[(unsigned)((1 + r) << 8) + (unsigned)t];

    float shprev = NEGF;   // shfl of boundary cell from previous row (row0: NEG)
    float carry  = NEGF;   // consumer: left-wave boundary of row i0-1

    // One DP row. CHECKF/GUARDF are literal bools (folded). Bv = left-wave
    // boundary value for this row (lane 0 only). Boundary cell c3 computed
    // FIRST; its shfl issued immediately (consumed next row -> latency hidden).
#define ROWX(r, CHECKF, GUARDF, Bv)                                             \
    {                                                                           \
        const int i = i0 + (r);                                                 \
        if (!(GUARDF) || (i < N_FRAMES)) {                                      \
            const unsigned long long u = ring[r];                               \
            if (!(GUARDF) || (i + CH < N_FRAMES))                               \
                ring[r] = gem[(unsigned)((i + CH) << 8) + (unsigned)t];         \
            const float e0 = H2F(u);       const float e1 = H2F(u >> 16);       \
            const float e2 = H2F(u >> 32); const float e3 = H2F(u >> 48);       \
            float c0, c1, c2, c3;                                               \
            LSECELL(c3, p2, p3, e3);                                            \
            const float shnext = __shfl_up(c3, 1);                              \
            LSECELL(c2, p1, p2, e2);                                            \
            LSECELL(c1, p0, p1, e1);                                            \
            const float left = (lane == 0) ? (Bv) : shprev;                     \
            LSECELL(c0, left, p0, e0);                                          \
            if (wlt3 && lane == 63) bpub[w][par][r] = c3;                       \
            if (CHECKF) {                                                       \
                if (i == inlen - 1 && t == fth) {                               \
                    float v_ = c0;                                              \
                    if (fcc == 1) v_ = c1;                                      \
                    if (fcc == 2) v_ = c2;                                      \
                    if (fcc == 3) v_ = c3;                                      \
                    ws_final[b] = v_ * LN2;                                     \
                }                                                               \
            }                                                                   \
            p0 = c0; p1 = c1; p2 = c2; p3 = c3; shprev = shnext;                \
        }                                                                       \
    }

#define BODY(CHECKF, GUARDF)                                                    \
    {                                                                           \
        ROWX(0,  CHECKF, GUARDF, B0)  ROWX(1,  CHECKF, GUARDF, B1)              \
        ROWX(2,  CHECKF, GUARDF, B2)  ROWX(3,  CHECKF, GUARDF, B3)              \
        ROWX(4,  CHECKF, GUARDF, B4)  ROWX(5,  CHECKF, GUARDF, B5)              \
        ROWX(6,  CHECKF, GUARDF, B6)  ROWX(7,  CHECKF, GUARDF, B7)              \
        ROWX(8,  CHECKF, GUARDF, B8)  ROWX(9,  CHECKF, GUARDF, B9)              \
        ROWX(10, CHECKF, GUARDF, B10) ROWX(11, CHECKF, GUARDF, B11)             \
        ROWX(12, CHECKF, GUARDF, B12) ROWX(13, CHECKF, GUARDF, B13)             \
        ROWX(14, CHECKF, GUARDF, B14) ROWX(15, CHECKF, GUARDF, B15)             \
    }

    for (int p = 0; p < NPH; ++p) {
        const int q = p - w;
        if (q >= 0 && q < NCH) {
            const int i0  = 1 + q * CH;
            const int par = q & 1;

            // left-wave boundary values for rows i0-1 .. i0+14
            float B0 = NEGF, B1 = NEGF, B2 = NEGF, B3 = NEGF,
                  B4 = NEGF, B5 = NEGF, B6 = NEGF, B7 = NEGF,
                  B8 = NEGF, B9 = NEGF, B10 = NEGF, B11 = NEGF,
                  B12 = NEGF, B13 = NEGF, B14 = NEGF, B15 = NEGF;
            if (w > 0) {
                const float* vp = &bpub[w - 1][par][0];
                B0 = carry;
                B1  = vp[0];  B2  = vp[1];  B3  = vp[2];  B4  = vp[3];
                B5  = vp[4];  B6  = vp[5];  B7  = vp[6];  B8  = vp[7];
                B9  = vp[8];  B10 = vp[9];  B11 = vp[10]; B12 = vp[11];
                B13 = vp[12]; B14 = vp[13]; B15 = vp[14];
                carry = vp[15];
            }

            const bool chk = ((unsigned)(inlen - 1 - i0) < (unsigned)CH);
            if (q < NCH - 2) {              // rows+refills all in range
                if (chk) BODY(true, false) else BODY(false, false)
            } else {                        // tail: guard rows/refills
                if (chk) BODY(true, true)  else BODY(false, true)
            }
        }
        // publish ds_writes (and B reads) retired before rendezvous;
        // raw barrier: vmcnt emit-ring loads stay in flight.
        asm volatile("s_waitcnt lgkmcnt(0)" ::: "memory");
        __builtin_amdgcn_s_barrier();
        asm volatile("" ::: "memory");
    }
#undef BODY
#undef ROWX
}

// Final scalar: out = -sum(ws_final)/BATCH. Unconditional write.
__global__ void reduce_kernel(const float* __restrict__ ws_final, float* __restrict__ out)
{
    if (threadIdx.x == 0 && blockIdx.x == 0) {
        float s = 0.0f;
        for (int b = 0; b < BATCH; ++b) s += ws_final[b];
        out[0] = -s / (float)BATCH;
    }
}

// ---------------- Fallback (verified R3 kernel) if ws too small ----------------
#define CELL(dst, A, U, E)                                            \
    {                                                                 \
        const float m_ = fmaxf((A), (U));                             \
        const float d_ = (A) - (U);                                   \
        const float p_ = __builtin_amdgcn_exp2f(-fabsf(d_));          \
        const float l_ = __builtin_amdgcn_logf(1.0f + p_);            \
        (dst) = fmaf((E), L2E, m_ + l_);                              \
    }

__global__ __launch_bounds__(256)
void align_dp4(const float* __restrict__ scores,
               const int*   __restrict__ targets,
               const int*   __restrict__ in_len,
               const int*   __restrict__ tg_len,
               float*       __restrict__ ws_final)
{
    constexpr float L2E = 1.44269504088896340736f;
    constexpr float LN2 = 0.69314718055994530942f;

    const int b    = blockIdx.x;
    const int t    = threadIdx.x;
    const int lane = t & 63;
    const int w    = t >> 6;

    __shared__ float elds[4][VOCAB];
    __shared__ float bnd[2][8];

    const int inlen = in_len[b];
    const int tlen  = tg_len[b];

    const gcfp gsc = (gcfp)scores;
    const unsigned base = (unsigned)(b * VOCAB);
    constexpr unsigned ROWW = (unsigned)(BATCH * VOCAB);

    int tok[4];
#pragma unroll
    for (int c = 0; c < 4; ++c) {
        const int col = t * 4 + c;
        tok[c] = targets[b * TARGET_LEN + (col < TARGET_LEN ? col : TARGET_LEN - 1)];
    }

    float prev[4];
#pragma unroll
    for (int c = 0; c < 4; ++c) prev[c] = NEGF;
    if (t == 0) prev[0] = gsc[base + (unsigned)tok[0]] * L2E;

    elds[1][t] = gsc[1u * ROWW + base + (unsigned)t];
    elds[2][t] = gsc[2u * ROWW + base + (unsigned)t];
    if (lane == 63) bnd[0][w] = NEGF;

    float g[4];
    g[3] = gsc[3u * ROWW + base + (unsigned)t];
    g[0] = gsc[4u * ROWW + base + (unsigned)t];
    g[1] = gsc[5u * ROWW + base + (unsigned)t];
    g[2] = gsc[6u * ROWW + base + (unsigned)t];

    const int fth = (tlen - 1) >> 2;
    const int fcc = (tlen - 1) & 3;

#define STEP(K)                                                                    \
    {                                                                              \
        const int i = ib + (K);                                                    \
        if (i < N_FRAMES) {                                                        \
            asm volatile("s_waitcnt lgkmcnt(0)" ::: "memory");                     \
            __builtin_amdgcn_s_barrier();                                          \
            asm volatile("" ::: "memory");                                         \
            const int sl = i & 3;                                                  \
            const float ec0 = elds[sl][tok[0]];                                    \
            const float ec1 = elds[sl][tok[1]];                                    \
            const float ec2 = elds[sl][tok[2]];                                    \
            const float ec3 = elds[sl][tok[3]];                                    \
            const float fromLds = (w > 0) ? bnd[(i - 1) & 1][w - 1] : NEGF;        \
            if (i + 2 < N_FRAMES) elds[(i + 2) & 3][t] = g[((K) + 3) & 3];         \
            if (i + 6 < N_FRAMES)                                                  \
                g[((K) + 3) & 3] = gsc[(unsigned)(i + 6) * ROWW + base + (unsigned)t]; \
            const float sh   = __shfl_up(prev[3], 1);                              \
            const float left = (lane == 0) ? fromLds : sh;                         \
            float cur0, cur1, cur2, cur3;                                          \
            CELL(cur0, left,    prev[0], ec0);                                     \
            CELL(cur1, prev[0], prev[1], ec1);                                     \
            CELL(cur2, prev[1], prev[2], ec2);                                     \
            CELL(cur3, prev[2], prev[3], ec3);                                     \
            if (lane == 63) bnd[i & 1][w] = cur3;                                  \
            if (i == inlen - 1 && t == fth) {                                      \
                const float v = (fcc == 0) ? cur0 : (fcc == 1) ? cur1              \
                              : (fcc == 2) ? cur2 : cur3;                          \
                ws_final[b] = v * LN2;                                             \
            }                                                                      \
            prev[0] = cur0; prev[1] = cur1; prev[2] = cur2; prev[3] = cur3;        \
        }                                                                          \
    }

    for (int ib = 1; ib < N_FRAMES; ib += 4) {
        STEP(0) STEP(1) STEP(2) STEP(3)
    }
#undef STEP
}

extern "C" void kernel_launch(void* const* d_in, const int* in_sizes, int n_in,
                              void* d_out, int out_size, void* d_ws, size_t ws_size,
                              hipStream_t stream)
{
    const float* scores  = (const float*)d_in[0];
    const int*   targets = (const int*)  d_in[1];
    const int*   in_len  = (const int*)  d_in[2];
    const int*   tg_len  = (const int*)  d_in[3];
    float*       out     = (float*)d_out;
    float*       ws_fin  = (float*)d_ws;                     // [0,256): per-batch finals

    const size_t emit_bytes = (size_t)BATCH * N_FRAMES * 1024 * sizeof(__half);
    const size_t need = 256 + emit_bytes;

    if (ws_size >= need) {
        __half* emit = (__half*)((char*)d_ws + 256);
        dim3 ggrid(N_FRAMES, BATCH);
        gather_emit<<<ggrid, 256, 0, stream>>>(scores, targets, emit);
        align_dp_4w<<<BATCH, 256, 0, stream>>>(emit, in_len, tg_len, ws_fin);
    } else {
        align_dp4<<<BATCH, 256, 0, stream>>>(scores, targets, in_len, tg_len, ws_fin);
    }
    reduce_kernel<<<1, 64, 0, stream>>>(ws_fin, out);
}

// Round 12
// 363.887 us; speedup vs baseline: 3.4331x; 1.0038x over previous
//
#include <hip/hip_runtime.h>
#include <hip/hip_fp16.h>

// Problem constants (from reference)
constexpr int N_FRAMES   = 2000;
constexpr int BATCH      = 32;
constexpr int TARGET_LEN = 1000;
constexpr int VOCAB      = 256;
constexpr int CH         = 16;                              // rows per chunk/phase
constexpr int NCH        = (N_FRAMES - 1 + CH - 1) / CH;    // 125
constexpr int NW         = 8;                               // waves (2 per SIMD)
constexpr int NPH        = NCH + (NW - 1);                  // 132 phases
#define NEGF (-1e30f)

// addrspace(1) pointers => guaranteed global_load (vmcnt only, never flat).
// Scalar element types only (HIP vector types can't bind addrspace(1) refs).
typedef __attribute__((address_space(1))) const float* gcfp;
typedef __attribute__((address_space(1))) const unsigned* gcu32;

// log2(1+x) on [0,1], degree-5 minimax, |err|<=1.6e-5 (validated R9/R10, absmax 0.0)
__device__ __forceinline__ float log2_1p(float x) {
    float t = fmaf(x, 0.0464048f, -0.1963066f);
    t = fmaf(x, t, 0.4176245f);
    t = fmaf(x, t, -0.7096745f);
    t = fmaf(x, t, 1.44196727f);
    return x * t;
}

// log2-domain logaddexp cell, emit E already premultiplied by log2(e):
//   dst = E + max(A,U) + log2(1 + 2^(-|A-U|))    [single trans: exp2]
#define LSECELL(dst, A, U, E)                                         \
    {                                                                 \
        const float m_ = fmaxf((A), (U));                             \
        const float d_ = (A) - (U);                                   \
        const float x_ = __builtin_amdgcn_exp2f(-fabsf(d_));          \
        (dst) = (E) + (m_ + log2_1p(x_));                             \
    }

#define H2F(us) __half2float(__ushort_as_half((unsigned short)(us)))

// ---------------- Phase 1: massively parallel emit gather ----------------
// emit[b][i][col] = fp16( scores[i,b,tgt[b][min(col,999)]] * log2(e) )
__global__ __launch_bounds__(256)
void gather_emit(const float* __restrict__ scores,
                 const int*   __restrict__ targets,
                 __half*      __restrict__ emit)
{
    constexpr float L2E = 1.44269504088896340736f;
    const int i = blockIdx.x;
    const int b = blockIdx.y;
    const int t = threadIdx.x;

    const gcfp gsc = (gcfp)scores;
    const unsigned sbase = (unsigned)(i * BATCH * VOCAB + b * VOCAB);

    int tk0, tk1, tk2, tk3;
    if (t < TARGET_LEN / 4) {
        const int4 tk = *(const int4*)&targets[b * TARGET_LEN + 4 * t];
        tk0 = tk.x; tk1 = tk.y; tk2 = tk.z; tk3 = tk.w;
    } else {
        tk0 = tk1 = tk2 = tk3 = targets[b * TARGET_LEN + TARGET_LEN - 1];
    }

    const float e0 = gsc[sbase + (unsigned)tk0] * L2E;
    const float e1 = gsc[sbase + (unsigned)tk1] * L2E;
    const float e2 = gsc[sbase + (unsigned)tk2] * L2E;
    const float e3 = gsc[sbase + (unsigned)tk3] * L2E;

    const unsigned long long h0 = __half_as_ushort(__float2half_rn(e0));
    const unsigned long long h1 = __half_as_ushort(__float2half_rn(e1));
    const unsigned long long h2 = __half_as_ushort(__float2half_rn(e2));
    const unsigned long long h3 = __half_as_ushort(__float2half_rn(e3));

    const unsigned long long u = h0 | (h1 << 16) | (h2 << 32) | (h3 << 48);
    *(unsigned long long*)(emit + (((size_t)(b * N_FRAMES + i)) << 10) + 4 * t) = u;
}

// ---------------- Phase 2: 8-wave skewed software-pipelined DP ----------------
// Wave w owns cols [128w, 128(w+1)), 2 cells/lane (col = 2t + c). 2 waves per
// SIMD so one wave's trans/shfl/dep stalls are covered by the other.
// Phase p: wave w computes chunk q=p-w (rows 1+16q .. 16+16q). Boundary column
// handoff wave w -> w+1 via bpub[w][q&1][16]; one raw s_barrier per phase
// (lgkmcnt-only drain; emit-ring vmcnt loads survive). Hot chunk bodies are
// branchless straight-line; shfl for row i+1 issued right after row i's c1.
__global__ __launch_bounds__(512)
void align_dp_8w(const __half* __restrict__ emit,   // [B][N][1024] premult
                 const int*    __restrict__ in_len,
                 const int*    __restrict__ tg_len,
                 float*        __restrict__ ws_final)
{
    constexpr float LN2 = 0.69314718055994530942f;

    const int b    = blockIdx.x;
    const int t    = threadIdx.x;            // 0..511
    const int lane = t & 63;
    const int w    = t >> 6;                 // 0..7
    const bool wpub = (w < NW - 1);

    __shared__ float bpub[NW - 1][2][CH];    // boundary handoff, parity dbuf (896B)

    const int inlen = in_len[b];
    const int tlen  = tg_len[b];
    const int fth   = (tlen - 1) >> 1;       // block-thread owning final column
    const int fcc   = (tlen - 1) & 1;

    // u32 index: i*512 + t   (2 packed fp16 per u32; cols 2t, 2t+1)
    const gcu32 gem = (gcu32)(emit + (((size_t)b * N_FRAMES) << 10));

    // ---- row 0: all NEG except global col 0 (value already *L2E) ----
    float p0 = NEGF, p1 = NEGF;
    if (t == 0) p0 = H2F(gem[0] & 0xffffu);

    // ---- emit ring: 16 rows in flight; slot r holds row (1+16q)+r ----
    unsigned ring[CH];
#pragma unroll
    for (int r = 0; r < CH; ++r) ring[r] = gem[(unsigned)((1 + r) << 9) + (unsigned)t];

    float shprev = NEGF;   // shfl of boundary cell from previous row (row0: NEG)
    float carry  = NEGF;   // consumer: left-wave boundary of row i0-1

    // One DP row. CHECKF/GUARDF are literal bools (folded). Bv = left-wave
    // boundary for this row (lane 0 only). c1 computed FIRST; its shfl issued
    // immediately (consumed next row -> latency hidden).
#define ROWX(r, CHECKF, GUARDF, Bv)                                             \
    {                                                                           \
        const int i = i0 + (r);                                                 \
        if (!(GUARDF) || (i < N_FRAMES)) {                                      \
            const unsigned u = ring[r];                                         \
            if (!(GUARDF) || (i + CH < N_FRAMES))                               \
                ring[r] = gem[(unsigned)((i + CH) << 9) + (unsigned)t];         \
            const float e0 = H2F(u & 0xffffu);                                  \
            const float e1 = H2F(u >> 16);                                      \
            float c0, c1;                                                       \
            LSECELL(c1, p0, p1, e1);                                            \
            const float shnext = __shfl_up(c1, 1);                              \
            const float left = (lane == 0) ? (Bv) : shprev;                     \
            LSECELL(c0, left, p0, e0);                                          \
            if (wpub && lane == 63) bpub[w][par][r] = c1;                       \
            if (CHECKF) {                                                       \
                if (i == inlen - 1 && t == fth)                                 \
                    ws_final[b] = (fcc ? c1 : c0) * LN2;                        \
            }                                                                   \
            p0 = c0; p1 = c1; shprev = shnext;                                  \
        }                                                                       \
    }

#define BODY(CHECKF, GUARDF)                                                    \
    {                                                                           \
        ROWX(0,  CHECKF, GUARDF, B0)  ROWX(1,  CHECKF, GUARDF, B1)              \
        ROWX(2,  CHECKF, GUARDF, B2)  ROWX(3,  CHECKF, GUARDF, B3)              \
        ROWX(4,  CHECKF, GUARDF, B4)  ROWX(5,  CHECKF, GUARDF, B5)              \
        ROWX(6,  CHECKF, GUARDF, B6)  ROWX(7,  CHECKF, GUARDF, B7)              \
        ROWX(8,  CHECKF, GUARDF, B8)  ROWX(9,  CHECKF, GUARDF, B9)              \
        ROWX(10, CHECKF, GUARDF, B10) ROWX(11, CHECKF, GUARDF, B11)             \
        ROWX(12, CHECKF, GUARDF, B12) ROWX(13, CHECKF, GUARDF, B13)             \
        ROWX(14, CHECKF, GUARDF, B14) ROWX(15, CHECKF, GUARDF, B15)             \
    }

    for (int p = 0; p < NPH; ++p) {
        const int q = p - w;
        if (q >= 0 && q < NCH) {
            const int i0  = 1 + q * CH;
            const int par = q & 1;

            // left-wave boundary values for rows i0-1 .. i0+14
            float B0 = NEGF, B1 = NEGF, B2 = NEGF, B3 = NEGF,
                  B4 = NEGF, B5 = NEGF, B6 = NEGF, B7 = NEGF,
                  B8 = NEGF, B9 = NEGF, B10 = NEGF, B11 = NEGF,
                  B12 = NEGF, B13 = NEGF, B14 = NEGF, B15 = NEGF;
            if (w > 0) {
                const float* vp = &bpub[w - 1][par][0];
                B0 = carry;
                B1  = vp[0];  B2  = vp[1];  B3  = vp[2];  B4  = vp[3];
                B5  = vp[4];  B6  = vp[5];  B7  = vp[6];  B8  = vp[7];
                B9  = vp[8];  B10 = vp[9];  B11 = vp[10]; B12 = vp[11];
                B13 = vp[12]; B14 = vp[13]; B15 = vp[14];
                carry = vp[15];
            }

            const bool chk = ((unsigned)(inlen - 1 - i0) < (unsigned)CH);
            if (q < NCH - 2) {              // rows+refills all in range
                if (chk) BODY(true, false) else BODY(false, false)
            } else {                        // tail: guard rows/refills
                if (chk) BODY(true, true)  else BODY(false, true)
            }
        }
        // publish ds_writes (and B reads) retired before rendezvous;
        // raw barrier: vmcnt emit-ring loads stay in flight.
        asm volatile("s_waitcnt lgkmcnt(0)" ::: "memory");
        __builtin_amdgcn_s_barrier();
        asm volatile("" ::: "memory");
    }
#undef BODY
#undef ROWX
}

// Final scalar: out = -sum(ws_final)/BATCH. Unconditional write.
__global__ void reduce_kernel(const float* __restrict__ ws_final, float* __restrict__ out)
{
    if (threadIdx.x == 0 && blockIdx.x == 0) {
        float s = 0.0f;
        for (int b = 0; b < BATCH; ++b) s += ws_final[b];
        out[0] = -s / (float)BATCH;
    }
}

// ---------------- Fallback (verified R3 kernel) if ws too small ----------------
#define CELL(dst, A, U, E)                                            \
    {                                                                 \
        const float m_ = fmaxf((A), (U));                             \
        const float d_ = (A) - (U);                                   \
        const float p_ = __builtin_amdgcn_exp2f(-fabsf(d_));          \
        const float l_ = __builtin_amdgcn_logf(1.0f + p_);            \
        (dst) = fmaf((E), L2E, m_ + l_);                              \
    }

__global__ __launch_bounds__(256)
void align_dp4(const float* __restrict__ scores,
               const int*   __restrict__ targets,
               const int*   __restrict__ in_len,
               const int*   __restrict__ tg_len,
               float*       __restrict__ ws_final)
{
    constexpr float L2E = 1.44269504088896340736f;
    constexpr float LN2 = 0.69314718055994530942f;

    const int b    = blockIdx.x;
    const int t    = threadIdx.x;
    const int lane = t & 63;
    const int w    = t >> 6;

    __shared__ float elds[4][VOCAB];
    __shared__ float bnd[2][8];

    const int inlen = in_len[b];
    const int tlen  = tg_len[b];

    const gcfp gsc = (gcfp)scores;
    const unsigned base = (unsigned)(b * VOCAB);
    constexpr unsigned ROWW = (unsigned)(BATCH * VOCAB);

    int tok[4];
#pragma unroll
    for (int c = 0; c < 4; ++c) {
        const int col = t * 4 + c;
        tok[c] = targets[b * TARGET_LEN + (col < TARGET_LEN ? col : TARGET_LEN - 1)];
    }

    float prev[4];
#pragma unroll
    for (int c = 0; c < 4; ++c) prev[c] = NEGF;
    if (t == 0) prev[0] = gsc[base + (unsigned)tok[0]] * L2E;

    elds[1][t] = gsc[1u * ROWW + base + (unsigned)t];
    elds[2][t] = gsc[2u * ROWW + base + (unsigned)t];
    if (lane == 63) bnd[0][w] = NEGF;

    float g[4];
    g[3] = gsc[3u * ROWW + base + (unsigned)t];
    g[0] = gsc[4u * ROWW + base + (unsigned)t];
    g[1] = gsc[5u * ROWW + base + (unsigned)t];
    g[2] = gsc[6u * ROWW + base + (unsigned)t];

    const int fth = (tlen - 1) >> 2;
    const int fcc = (tlen - 1) & 3;

#define STEP(K)                                                                    \
    {                                                                              \
        const int i = ib + (K);                                                    \
        if (i < N_FRAMES) {                                                        \
            asm volatile("s_waitcnt lgkmcnt(0)" ::: "memory");                     \
            __builtin_amdgcn_s_barrier();                                          \
            asm volatile("" ::: "memory");                                         \
            const int sl = i & 3;                                                  \
            const float ec0 = elds[sl][tok[0]];                                    \
            const float ec1 = elds[sl][tok[1]];                                    \
            const float ec2 = elds[sl][tok[2]];                                    \
            const float ec3 = elds[sl][tok[3]];                                    \
            const float fromLds = (w > 0) ? bnd[(i - 1) & 1][w - 1] : NEGF;        \
            if (i + 2 < N_FRAMES) elds[(i + 2) & 3][t] = g[((K) + 3) & 3];         \
            if (i + 6 < N_FRAMES)                                                  \
                g[((K) + 3) & 3] = gsc[(unsigned)(i + 6) * ROWW + base + (unsigned)t]; \
            const float sh   = __shfl_up(prev[3], 1);                              \
            const float left = (lane == 0) ? fromLds : sh;                         \
            float cur0, cur1, cur2, cur3;                                          \
            CELL(cur0, left,    prev[0], ec0);                                     \
            CELL(cur1, prev[0], prev[1], ec1);                                     \
            CELL(cur2, prev[1], prev[2], ec2);                                     \
            CELL(cur3, prev[2], prev[3], ec3);                                     \
            if (lane == 63) bnd[i & 1][w] = cur3;                                  \
            if (i == inlen - 1 && t == fth) {                                      \
                const float v = (fcc == 0) ? cur0 : (fcc == 1) ? cur1              \
                              : (fcc == 2) ? cur2 : cur3;                          \
                ws_final[b] = v * LN2;                                             \
            }                                                                      \
            prev[0] = cur0; prev[1] = cur1; prev[2] = cur2; prev[3] = cur3;        \
        }                                                                          \
    }

    for (int ib = 1; ib < N_FRAMES; ib += 4) {
        STEP(0) STEP(1) STEP(2) STEP(3)
    }
#undef STEP
}

extern "C" void kernel_launch(void* const* d_in, const int* in_sizes, int n_in,
                              void* d_out, int out_size, void* d_ws, size_t ws_size,
                              hipStream_t stream)
{
    const float* scores  = (const float*)d_in[0];
    const int*   targets = (const int*)  d_in[1];
    const int*   in_len  = (const int*)  d_in[2];
    const int*   tg_len  = (const int*)  d_in[3];
    float*       out     = (float*)d_out;
    float*       ws_fin  = (float*)d_ws;                     // [0,256): per-batch finals

    const size_t emit_bytes = (size_t)BATCH * N_FRAMES * 1024 * sizeof(__half);
    const size_t need = 256 + emit_bytes;

    if (ws_size >= need) {
        __half* emit = (__half*)((char*)d_ws + 256);
        dim3 ggrid(N_FRAMES, BATCH);
        gather_emit<<<ggrid, 256, 0, stream>>>(scores, targets, emit);
        align_dp_8w<<<BATCH, 512, 0, stream>>>(emit, in_len, tg_len, ws_fin);
    } else {
        align_dp4<<<BATCH, 256, 0, stream>>>(scores, targets, in_len, tg_len, ws_fin);
    }
    reduce_kernel<<<1, 64, 0, stream>>>(ws_fin, out);
}

// Round 13
// 350.203 us; speedup vs baseline: 3.5673x; 1.0391x over previous
//
#include <hip/hip_runtime.h>
#include <hip/hip_fp16.h>

// Problem constants (from reference)
constexpr int N_FRAMES   = 2000;
constexpr int BATCH      = 32;
constexpr int TARGET_LEN = 1000;
constexpr int VOCAB      = 256;
constexpr int CH         = 16;                              // rows per chunk/phase
constexpr int NCH        = (N_FRAMES - 1 + CH - 1) / CH;    // 125
constexpr int NW         = 8;                               // waves (2 per SIMD)
constexpr int NPH        = NCH + (NW - 1);                  // 132 phases
#define NEGF (-1e30f)

// addrspace(1) pointers => guaranteed global_load (vmcnt only, never flat).
// Scalar element types only (HIP vector types can't bind addrspace(1) refs).
typedef __attribute__((address_space(1))) const float* gcfp;
typedef __attribute__((address_space(1))) const unsigned* gcu32;

typedef float f32x2 __attribute__((ext_vector_type(2)));

#define H2F(us) __half2float(__ushort_as_half((unsigned short)(us)))

// Both cells of a lane, packed-FP32 form. c.x = LSE(A.x,U.x)+E.x, etc.
// <2 x float> sub/add/fma lower to v_pk_add_f32 / v_pk_fma_f32 on gfx950
// (full-rate VOPP); max stays 2x v_max_f32 (no pk_max_f32); exp2 stays 2x
// scalar trans with FREE -|d| input modifiers. Poly = log2(1+x) minimax
// (validated R9-R11, absmax 0.0); final mul folds into pk_fma with s=E+m.
__device__ __forceinline__ f32x2 lse2pk(f32x2 A, f32x2 U, f32x2 E) {
    f32x2 m; m.x = fmaxf(A.x, U.x); m.y = fmaxf(A.y, U.y);
    const f32x2 d = A - U;                       // v_pk_add_f32 (neg)
    f32x2 x;
    x.x = __builtin_amdgcn_exp2f(-fabsf(d.x));   // modifiers are free
    x.y = __builtin_amdgcn_exp2f(-fabsf(d.y));
    const f32x2 s = E + m;                       // v_pk_add_f32
    f32x2 tt = x * 0.0464048f - 0.1963066f;      // v_pk_fma_f32 (contract)
    tt = x * tt + 0.4176245f;
    tt = x * tt - 0.7096745f;
    tt = x * tt + 1.44196727f;
    return x * tt + s;                           // v_pk_fma_f32
}

// ---------------- Phase 1: massively parallel emit gather ----------------
// emit[b][i][col] = fp16( scores[i,b,tgt[b][min(col,999)]] * log2(e) )
__global__ __launch_bounds__(256)
void gather_emit(const float* __restrict__ scores,
                 const int*   __restrict__ targets,
                 __half*      __restrict__ emit)
{
    constexpr float L2E = 1.44269504088896340736f;
    const int i = blockIdx.x;
    const int b = blockIdx.y;
    const int t = threadIdx.x;

    const gcfp gsc = (gcfp)scores;
    const unsigned sbase = (unsigned)(i * BATCH * VOCAB + b * VOCAB);

    int tk0, tk1, tk2, tk3;
    if (t < TARGET_LEN / 4) {
        const int4 tk = *(const int4*)&targets[b * TARGET_LEN + 4 * t];
        tk0 = tk.x; tk1 = tk.y; tk2 = tk.z; tk3 = tk.w;
    } else {
        tk0 = tk1 = tk2 = tk3 = targets[b * TARGET_LEN + TARGET_LEN - 1];
    }

    const float e0 = gsc[sbase + (unsigned)tk0] * L2E;
    const float e1 = gsc[sbase + (unsigned)tk1] * L2E;
    const float e2 = gsc[sbase + (unsigned)tk2] * L2E;
    const float e3 = gsc[sbase + (unsigned)tk3] * L2E;

    const unsigned long long h0 = __half_as_ushort(__float2half_rn(e0));
    const unsigned long long h1 = __half_as_ushort(__float2half_rn(e1));
    const unsigned long long h2 = __half_as_ushort(__float2half_rn(e2));
    const unsigned long long h3 = __half_as_ushort(__float2half_rn(e3));

    const unsigned long long u = h0 | (h1 << 16) | (h2 << 32) | (h3 << 48);
    *(unsigned long long*)(emit + (((size_t)(b * N_FRAMES + i)) << 10) + 4 * t) = u;
}

// ---------------- Phase 2: 8-wave skewed DP, packed-FP32 cells ----------------
// Wave w owns cols [128w, 128(w+1)), 2 cells/lane (col = 2t + c). Skeleton
// verified in R10/R11: deterministic chunk pipeline, branchless folded bodies,
// cross-row pipelined shfl, raw barrier + lgkm-only drain per phase (emit-ring
// vmcnt loads survive). New: pk-vectorized cell math + batched boundary publish
// (one 16-write block per chunk instead of per-row exec-masked writes).
__global__ __launch_bounds__(512)
void align_dp_8w(const __half* __restrict__ emit,   // [B][N][1024] premult
                 const int*    __restrict__ in_len,
                 const int*    __restrict__ tg_len,
                 float*        __restrict__ ws_final)
{
    constexpr float LN2 = 0.69314718055994530942f;

    const int b    = blockIdx.x;
    const int t    = threadIdx.x;            // 0..511
    const int lane = t & 63;
    const int w    = t >> 6;                 // 0..7
    const bool wpub = (w < NW - 1);

    __shared__ float bpub[NW - 1][2][CH];    // boundary handoff, parity dbuf (896B)

    const int inlen = in_len[b];
    const int tlen  = tg_len[b];
    const int fth   = (tlen - 1) >> 1;       // block-thread owning final column
    const int fcc   = (tlen - 1) & 1;

    // u32 index: i*512 + t   (2 packed fp16 per u32; cols 2t, 2t+1)
    const gcu32 gem = (gcu32)(emit + (((size_t)b * N_FRAMES) << 10));

    // ---- row 0: all NEG except global col 0 (value already *L2E) ----
    float p0 = NEGF, p1 = NEGF;
    if (t == 0) p0 = H2F(gem[0] & 0xffffu);

    // ---- emit ring: 16 rows in flight; slot r holds row (1+16q)+r ----
    unsigned ring[CH];
#pragma unroll
    for (int r = 0; r < CH; ++r) ring[r] = gem[(unsigned)((1 + r) << 9) + (unsigned)t];

    float shprev = NEGF;   // shfl of boundary cell from previous row (row0: NEG)
    float carry  = NEGF;   // consumer: left-wave boundary of row i0-1

    // One DP row, pk pair. CHECKF/GUARDF literal bools (folded). Bv = left-wave
    // boundary for this row (lane 0 only). Ov = this row's boundary cell (c.y),
    // kept in a register and published once per chunk.
#define ROWX(r, CHECKF, GUARDF, Bv, Ov)                                         \
    {                                                                           \
        const int i = i0 + (r);                                                 \
        if (!(GUARDF) || (i < N_FRAMES)) {                                      \
            const unsigned u = ring[r];                                         \
            if (!(GUARDF) || (i + CH < N_FRAMES))                               \
                ring[r] = gem[(unsigned)((i + CH) << 9) + (unsigned)t];         \
            f32x2 E; E.x = H2F(u & 0xffffu); E.y = H2F(u >> 16);                \
            f32x2 A; A.x = (lane == 0) ? (Bv) : shprev; A.y = p0;               \
            f32x2 U; U.x = p0; U.y = p1;                                        \
            const f32x2 c = lse2pk(A, U, E);                                    \
            shprev = __shfl_up(c.y, 1);                                         \
            (Ov) = c.y;                                                         \
            if (CHECKF) {                                                       \
                if (i == inlen - 1 && t == fth)                                 \
                    ws_final[b] = (fcc ? c.y : c.x) * LN2;                      \
            }                                                                   \
            p0 = c.x; p1 = c.y;                                                 \
        } else { (Ov) = NEGF; }                                                 \
    }

#define BODY(CHECKF, GUARDF)                                                    \
    {                                                                           \
        ROWX(0,  CHECKF, GUARDF, B0,  o0)  ROWX(1,  CHECKF, GUARDF, B1,  o1)    \
        ROWX(2,  CHECKF, GUARDF, B2,  o2)  ROWX(3,  CHECKF, GUARDF, B3,  o3)    \
        ROWX(4,  CHECKF, GUARDF, B4,  o4)  ROWX(5,  CHECKF, GUARDF, B5,  o5)    \
        ROWX(6,  CHECKF, GUARDF, B6,  o6)  ROWX(7,  CHECKF, GUARDF, B7,  o7)    \
        ROWX(8,  CHECKF, GUARDF, B8,  o8)  ROWX(9,  CHECKF, GUARDF, B9,  o9)    \
        ROWX(10, CHECKF, GUARDF, B10, o10) ROWX(11, CHECKF, GUARDF, B11, o11)   \
        ROWX(12, CHECKF, GUARDF, B12, o12) ROWX(13, CHECKF, GUARDF, B13, o13)   \
        ROWX(14, CHECKF, GUARDF, B14, o14) ROWX(15, CHECKF, GUARDF, B15, o15)   \
    }

    for (int p = 0; p < NPH; ++p) {
        const int q = p - w;
        if (q >= 0 && q < NCH) {
            const int i0  = 1 + q * CH;
            const int par = q & 1;

            // left-wave boundary values for rows i0-1 .. i0+14
            float B0 = NEGF, B1 = NEGF, B2 = NEGF, B3 = NEGF,
                  B4 = NEGF, B5 = NEGF, B6 = NEGF, B7 = NEGF,
                  B8 = NEGF, B9 = NEGF, B10 = NEGF, B11 = NEGF,
                  B12 = NEGF, B13 = NEGF, B14 = NEGF, B15 = NEGF;
            if (w > 0) {
                const float* vp = &bpub[w - 1][par][0];
                B0 = carry;
                B1  = vp[0];  B2  = vp[1];  B3  = vp[2];  B4  = vp[3];
                B5  = vp[4];  B6  = vp[5];  B7  = vp[6];  B8  = vp[7];
                B9  = vp[8];  B10 = vp[9];  B11 = vp[10]; B12 = vp[11];
                B13 = vp[12]; B14 = vp[13]; B15 = vp[14];
                carry = vp[15];
            }

            float o0, o1, o2, o3, o4, o5, o6, o7,
                  o8, o9, o10, o11, o12, o13, o14, o15;

            const bool chk = ((unsigned)(inlen - 1 - i0) < (unsigned)CH);
            if (q < NCH - 2) {              // rows+refills all in range
                if (chk) BODY(true, false) else BODY(false, false)
            } else {                        // tail: guard rows/refills
                if (chk) BODY(true, true)  else BODY(false, true)
            }

            // batched boundary publish: one exec-mask region per chunk
            if (wpub && lane == 63) {
                float* dp = &bpub[w][par][0];
                dp[0]  = o0;  dp[1]  = o1;  dp[2]  = o2;  dp[3]  = o3;
                dp[4]  = o4;  dp[5]  = o5;  dp[6]  = o6;  dp[7]  = o7;
                dp[8]  = o8;  dp[9]  = o9;  dp[10] = o10; dp[11] = o11;
                dp[12] = o12; dp[13] = o13; dp[14] = o14; dp[15] = o15;
            }
        }
        // publish ds_writes (and B reads) retired before rendezvous;
        // raw barrier: vmcnt emit-ring loads stay in flight.
        asm volatile("s_waitcnt lgkmcnt(0)" ::: "memory");
        __builtin_amdgcn_s_barrier();
        asm volatile("" ::: "memory");
    }
#undef BODY
#undef ROWX
}

// Final scalar: out = -sum(ws_final)/BATCH. Unconditional write.
__global__ void reduce_kernel(const float* __restrict__ ws_final, float* __restrict__ out)
{
    if (threadIdx.x == 0 && blockIdx.x == 0) {
        float s = 0.0f;
        for (int b = 0; b < BATCH; ++b) s += ws_final[b];
        out[0] = -s / (float)BATCH;
    }
}

// ---------------- Fallback (verified R3 kernel) if ws too small ----------------
#define CELL(dst, A, U, E)                                            \
    {                                                                 \
        const float m_ = fmaxf((A), (U));                             \
        const float d_ = (A) - (U);                                   \
        const float p_ = __builtin_amdgcn_exp2f(-fabsf(d_));          \
        const float l_ = __builtin_amdgcn_logf(1.0f + p_);            \
        (dst) = fmaf((E), L2E, m_ + l_);                              \
    }

__global__ __launch_bounds__(256)
void align_dp4(const float* __restrict__ scores,
               const int*   __restrict__ targets,
               const int*   __restrict__ in_len,
               const int*   __restrict__ tg_len,
               float*       __restrict__ ws_final)
{
    constexpr float L2E = 1.44269504088896340736f;
    constexpr float LN2 = 0.69314718055994530942f;

    const int b    = blockIdx.x;
    const int t    = threadIdx.x;
    const int lane = t & 63;
    const int w    = t >> 6;

    __shared__ float elds[4][VOCAB];
    __shared__ float bnd[2][8];

    const int inlen = in_len[b];
    const int tlen  = tg_len[b];

    const gcfp gsc = (gcfp)scores;
    const unsigned base = (unsigned)(b * VOCAB);
    constexpr unsigned ROWW = (unsigned)(BATCH * VOCAB);

    int tok[4];
#pragma unroll
    for (int c = 0; c < 4; ++c) {
        const int col = t * 4 + c;
        tok[c] = targets[b * TARGET_LEN + (col < TARGET_LEN ? col : TARGET_LEN - 1)];
    }

    float prev[4];
#pragma unroll
    for (int c = 0; c < 4; ++c) prev[c] = NEGF;
    if (t == 0) prev[0] = gsc[base + (unsigned)tok[0]] * L2E;

    elds[1][t] = gsc[1u * ROWW + base + (unsigned)t];
    elds[2][t] = gsc[2u * ROWW + base + (unsigned)t];
    if (lane == 63) bnd[0][w] = NEGF;

    float g[4];
    g[3] = gsc[3u * ROWW + base + (unsigned)t];
    g[0] = gsc[4u * ROWW + base + (unsigned)t];
    g[1] = gsc[5u * ROWW + base + (unsigned)t];
    g[2] = gsc[6u * ROWW + base + (unsigned)t];

    const int fth = (tlen - 1) >> 2;
    const int fcc = (tlen - 1) & 3;

#define STEP(K)                                                                    \
    {                                                                              \
        const int i = ib + (K);                                                    \
        if (i < N_FRAMES) {                                                        \
            asm volatile("s_waitcnt lgkmcnt(0)" ::: "memory");                     \
            __builtin_amdgcn_s_barrier();                                          \
            asm volatile("" ::: "memory");                                         \
            const int sl = i & 3;                                                  \
            const float ec0 = elds[sl][tok[0]];                                    \
            const float ec1 = elds[sl][tok[1]];                                    \
            const float ec2 = elds[sl][tok[2]];                                    \
            const float ec3 = elds[sl][tok[3]];                                    \
            const float fromLds = (w > 0) ? bnd[(i - 1) & 1][w - 1] : NEGF;        \
            if (i + 2 < N_FRAMES) elds[(i + 2) & 3][t] = g[((K) + 3) & 3];         \
            if (i + 6 < N_FRAMES)                                                  \
                g[((K) + 3) & 3] = gsc[(unsigned)(i + 6) * ROWW + base + (unsigned)t]; \
            const float sh   = __shfl_up(prev[3], 1);                              \
            const float left = (lane == 0) ? fromLds : sh;                         \
            float cur0, cur1, cur2, cur3;                                          \
            CELL(cur0, left,    prev[0], ec0);                                     \
            CELL(cur1, prev[0], prev[1], ec1);                                     \
            CELL(cur2, prev[1], prev[2], ec2);                                     \
            CELL(cur3, prev[2], prev[3], ec3);                                     \
            if (lane == 63) bnd[i & 1][w] = cur3;                                  \
            if (i == inlen - 1 && t == fth) {                                      \
                const float v = (fcc == 0) ? cur0 : (fcc == 1) ? cur1              \
                              : (fcc == 2) ? cur2 : cur3;                          \
                ws_final[b] = v * LN2;                                             \
            }                                                                      \
            prev[0] = cur0; prev[1] = cur1; prev[2] = cur2; prev[3] = cur3;        \
        }                                                                          \
    }

    for (int ib = 1; ib < N_FRAMES; ib += 4) {
        STEP(0) STEP(1) STEP(2) STEP(3)
    }
#undef STEP
}

extern "C" void kernel_launch(void* const* d_in, const int* in_sizes, int n_in,
                              void* d_out, int out_size, void* d_ws, size_t ws_size,
                              hipStream_t stream)
{
    const float* scores  = (const float*)d_in[0];
    const int*   targets = (const int*)  d_in[1];
    const int*   in_len  = (const int*)  d_in[2];
    const int*   tg_len  = (const int*)  d_in[3];
    float*       out     = (float*)d_out;
    float*       ws_fin  = (float*)d_ws;                     // [0,256): per-batch finals

    const size_t emit_bytes = (size_t)BATCH * N_FRAMES * 1024 * sizeof(__half);
    const size_t need = 256 + emit_bytes;

    if (ws_size >= need) {
        __half* emit = (__half*)((char*)d_ws + 256);
        dim3 ggrid(N_FRAMES, BATCH);
        gather_emit<<<ggrid, 256, 0, stream>>>(scores, targets, emit);
        align_dp_8w<<<BATCH, 512, 0, stream>>>(emit, in_len, tg_len, ws_fin);
    } else {
        align_dp4<<<BATCH, 256, 0, stream>>>(scores, targets, in_len, tg_len, ws_fin);
    }
    reduce_kernel<<<1, 64, 0, stream>>>(ws_fin, out);
}

// Round 14
// 202.695 us; speedup vs baseline: 6.1633x; 1.7277x over previous
//
#include <hip/hip_runtime.h>
#include <hip/hip_fp16.h>

// Problem constants (from reference)
constexpr int N_FRAMES   = 2000;
constexpr int BATCH      = 32;
constexpr int TARGET_LEN = 1000;
constexpr int VOCAB      = 256;
constexpr int CH         = 16;       // rows per chunk/phase
constexpr int NW         = 8;        // waves per block (2 per SIMD)
#define NEGF (-1e30f)

// addrspace(1) pointers => guaranteed global_load (vmcnt only, never flat).
typedef __attribute__((address_space(1))) const float* gcfp;
typedef __attribute__((address_space(1))) const unsigned* gcu32;

typedef float f32x2 __attribute__((ext_vector_type(2)));

#define H2F(us) __half2float(__ushort_as_half((unsigned short)(us)))

// Packed LSE pair in log2 domain (poly validated R9-R12, absmax 0.0):
// lse_e:    c = E + max(A,U) + log2(1+2^-|A-U|)
// lse_core: c =     max(A,U) + log2(1+2^-|A-U|)
__device__ __forceinline__ f32x2 lse_e(f32x2 A, f32x2 U, f32x2 E) {
    f32x2 m; m.x = fmaxf(A.x, U.x); m.y = fmaxf(A.y, U.y);
    const f32x2 d = A - U;
    f32x2 x;
    x.x = __builtin_amdgcn_exp2f(-fabsf(d.x));
    x.y = __builtin_amdgcn_exp2f(-fabsf(d.y));
    const f32x2 s = E + m;
    f32x2 tt = x * 0.0464048f - 0.1963066f;
    tt = x * tt + 0.4176245f;
    tt = x * tt - 0.7096745f;
    tt = x * tt + 1.44196727f;
    return x * tt + s;
}
__device__ __forceinline__ f32x2 lse_core(f32x2 A, f32x2 U) {
    f32x2 m; m.x = fmaxf(A.x, U.x); m.y = fmaxf(A.y, U.y);
    const f32x2 d = A - U;
    f32x2 x;
    x.x = __builtin_amdgcn_exp2f(-fabsf(d.x));
    x.y = __builtin_amdgcn_exp2f(-fabsf(d.y));
    f32x2 tt = x * 0.0464048f - 0.1963066f;
    tt = x * tt + 0.4176245f;
    tt = x * tt - 0.7096745f;
    tt = x * tt + 1.44196727f;
    return x * tt + m;
}

// ---------------- Phase 1: massively parallel emit gather ----------------
// emit[b][i][col] = fp16( scores[i,b,tgt[b][min(col,999)]] * log2(e) )
__global__ __launch_bounds__(256)
void gather_emit(const float* __restrict__ scores,
                 const int*   __restrict__ targets,
                 __half*      __restrict__ emit)
{
    constexpr float L2E = 1.44269504088896340736f;
    const int i = blockIdx.x;
    const int b = blockIdx.y;
    const int t = threadIdx.x;

    const gcfp gsc = (gcfp)scores;
    const unsigned sbase = (unsigned)(i * BATCH * VOCAB + b * VOCAB);

    int tk0, tk1, tk2, tk3;
    if (t < TARGET_LEN / 4) {
        const int4 tk = *(const int4*)&targets[b * TARGET_LEN + 4 * t];
        tk0 = tk.x; tk1 = tk.y; tk2 = tk.z; tk3 = tk.w;
    } else {
        tk0 = tk1 = tk2 = tk3 = targets[b * TARGET_LEN + TARGET_LEN - 1];
    }

    const float e0 = gsc[sbase + (unsigned)tk0] * L2E;
    const float e1 = gsc[sbase + (unsigned)tk1] * L2E;
    const float e2 = gsc[sbase + (unsigned)tk2] * L2E;
    const float e3 = gsc[sbase + (unsigned)tk3] * L2E;

    const unsigned long long h0 = __half_as_ushort(__float2half_rn(e0));
    const unsigned long long h1 = __half_as_ushort(__float2half_rn(e1));
    const unsigned long long h2 = __half_as_ushort(__float2half_rn(e2));
    const unsigned long long h3 = __half_as_ushort(__float2half_rn(e3));

    const unsigned long long u = h0 | (h1 << 16) | (h2 << 32) | (h3 << 48);
    *(unsigned long long*)(emit + (((size_t)(b * N_FRAMES + i)) << 10) + 4 * t) = u;
}

// ---------------- Phase 2: forward+backward halves, one launch ----------------
// grid (BATCH, 2): y==0 forward rows 1..m -> wsA = alpha[m,*];
//                  y==1 backward rows inlen-2..m -> wsB = beta[m,*].
// Both use the verified R12 skeleton: 8 waves x 2 cols/lane, deterministic
// skewed CH=16 chunks, branchless folded bodies, pk cells, raw s_barrier +
// lgkm-only drain per phase (emit-ring vmcnt loads survive).
__global__ __launch_bounds__(512)
void align_dp_fb(const __half* __restrict__ emit,   // [B][N][1024] premult L2E
                 const int*    __restrict__ in_len,
                 const int*    __restrict__ tg_len,
                 float*        __restrict__ wsA,    // [B][1024]
                 float*        __restrict__ wsB)    // [B][1024]
{
    const int b    = blockIdx.x;
    const int t    = threadIdx.x;            // 0..511
    const int lane = t & 63;
    const int w    = t >> 6;                 // 0..7

    __shared__ float bpub[NW - 1][2][CH];

    const int inlen = in_len[b];
    const int m     = (inlen - 1) >> 1;      // cut row (499..999)

    const gcu32 gem = (gcu32)(emit + (((size_t)b * N_FRAMES) << 10));

    if (blockIdx.y == 0) {
        // ================= FORWARD: alpha rows 1..m =================
        const int NCHf = (m + CH - 1) / CH;
        float p0 = NEGF, p1 = NEGF;
        if (t == 0) p0 = H2F(gem[0] & 0xffffu);

        unsigned ring[CH];
#pragma unroll
        for (int r = 0; r < CH; ++r) ring[r] = gem[(unsigned)((1 + r) << 9) + (unsigned)t];

        float shprev = NEGF, carry = NEGF;
        f32x2* wsA2 = (f32x2*)(wsA + (b << 10));

        // all rows/refills in-range (i <= m+15 <= 1014, +16 < 2000): no guards
#define FROWX(r, SNAPF, Bv, Ov)                                                 \
        {                                                                       \
            const int i = i0 + (r);                                             \
            const unsigned u = ring[r];                                         \
            ring[r] = gem[(unsigned)((i + CH) << 9) + (unsigned)t];             \
            f32x2 E; E.x = H2F(u & 0xffffu); E.y = H2F(u >> 16);                \
            f32x2 A; A.x = (lane == 0) ? (Bv) : shprev; A.y = p0;               \
            f32x2 U; U.x = p0; U.y = p1;                                        \
            const f32x2 c = lse_e(A, U, E);                                     \
            shprev = __shfl_up(c.y, 1);                                         \
            (Ov) = c.y;                                                         \
            if (SNAPF) { if (i == m) wsA2[t] = c; }                             \
            p0 = c.x; p1 = c.y;                                                 \
        }

#define FBODY(SNAPF)                                                            \
        {                                                                       \
            FROWX(0,  SNAPF, B0,  o0)  FROWX(1,  SNAPF, B1,  o1)                \
            FROWX(2,  SNAPF, B2,  o2)  FROWX(3,  SNAPF, B3,  o3)                \
            FROWX(4,  SNAPF, B4,  o4)  FROWX(5,  SNAPF, B5,  o5)                \
            FROWX(6,  SNAPF, B6,  o6)  FROWX(7,  SNAPF, B7,  o7)                \
            FROWX(8,  SNAPF, B8,  o8)  FROWX(9,  SNAPF, B9,  o9)                \
            FROWX(10, SNAPF, B10, o10) FROWX(11, SNAPF, B11, o11)               \
            FROWX(12, SNAPF, B12, o12) FROWX(13, SNAPF, B13, o13)               \
            FROWX(14, SNAPF, B14, o14) FROWX(15, SNAPF, B15, o15)               \
        }

        const int NPHf = NCHf + NW - 1;
        for (int p = 0; p < NPHf; ++p) {
            const int q = p - w;
            if (q >= 0 && q < NCHf) {
                const int i0  = 1 + q * CH;
                const int par = q & 1;

                float B0 = NEGF, B1 = NEGF, B2 = NEGF, B3 = NEGF,
                      B4 = NEGF, B5 = NEGF, B6 = NEGF, B7 = NEGF,
                      B8 = NEGF, B9 = NEGF, B10 = NEGF, B11 = NEGF,
                      B12 = NEGF, B13 = NEGF, B14 = NEGF, B15 = NEGF;
                if (w > 0) {
                    const float* vp = &bpub[w - 1][par][0];
                    B0 = carry;
                    B1  = vp[0];  B2  = vp[1];  B3  = vp[2];  B4  = vp[3];
                    B5  = vp[4];  B6  = vp[5];  B7  = vp[6];  B8  = vp[7];
                    B9  = vp[8];  B10 = vp[9];  B11 = vp[10]; B12 = vp[11];
                    B13 = vp[12]; B14 = vp[13]; B15 = vp[14];
                    carry = vp[15];
                }

                float o0, o1, o2, o3, o4, o5, o6, o7,
                      o8, o9, o10, o11, o12, o13, o14, o15;

                if (q == NCHf - 1) FBODY(true) else FBODY(false)

                if (w < NW - 1 && lane == 63) {
                    float* dp = &bpub[w][par][0];
                    dp[0]  = o0;  dp[1]  = o1;  dp[2]  = o2;  dp[3]  = o3;
                    dp[4]  = o4;  dp[5]  = o5;  dp[6]  = o6;  dp[7]  = o7;
                    dp[8]  = o8;  dp[9]  = o9;  dp[10] = o10; dp[11] = o11;
                    dp[12] = o12; dp[13] = o13; dp[14] = o14; dp[15] = o15;
                }
            }
            asm volatile("s_waitcnt lgkmcnt(0)" ::: "memory");
            __builtin_amdgcn_s_barrier();
            asm volatile("" ::: "memory");
        }
#undef FBODY
#undef FROWX
    } else {
        // ================= BACKWARD: beta rows inlen-2..m =================
        const int tlen   = tg_len[b];
        const int istart = inlen - 1;
        const int NCHb   = (istart - m + CH - 1) / CH;
        const int fth    = (tlen - 1) >> 1;
        const int fcc    = (tlen - 1) & 1;

        float p0 = NEGF, p1 = NEGF;
        if (t == fth) { if (fcc == 0) p0 = 0.0f; else p1 = 0.0f; }

        unsigned ring[CH];
#pragma unroll
        for (int r = 0; r < CH; ++r)
            ring[r] = gem[(unsigned)((istart - r) << 9) + (unsigned)t];

        f32x2* wsB2 = (f32x2*)(wsB + (b << 10));

        // beta[i,j] = LSE(x_j, x_{j+1}), x_j = e[i+1,j] + beta[i+1,j].
        // x computed at row start -> shfl_down issued early; publish x.x (lane0).
        // Rows below m in tail chunk compute junk AFTER snapshot (harmless);
        // all ring refills stay in-bounds (e-rows >= m-29 >= 0): no guards.
#define BROWX(r, SNAPF, Bv, Ov)                                                 \
        {                                                                       \
            const int i = i0 - (r);                                             \
            const unsigned u = ring[r];                                         \
            ring[r] = gem[(unsigned)((i + 1 - CH) << 9) + (unsigned)t];         \
            f32x2 E; E.x = H2F(u & 0xffffu); E.y = H2F(u >> 16);                \
            f32x2 P; P.x = p0; P.y = p1;                                        \
            const f32x2 x = E + P;                                              \
            const float sh = __shfl_down(x.x, 1);                               \
            (Ov) = x.x;                                                         \
            const float xR = (lane == 63) ? (Bv) : sh;                          \
            f32x2 A; A.x = x.x; A.y = x.y;                                      \
            f32x2 U; U.x = x.y; U.y = xR;                                       \
            const f32x2 c = lse_core(A, U);                                     \
            if (SNAPF) { if (i == m) wsB2[t] = c; }                             \
            p0 = c.x; p1 = c.y;                                                 \
        }

#define BBODY(SNAPF)                                                            \
        {                                                                       \
            BROWX(0,  SNAPF, B0,  o0)  BROWX(1,  SNAPF, B1,  o1)                \
            BROWX(2,  SNAPF, B2,  o2)  BROWX(3,  SNAPF, B3,  o3)                \
            BROWX(4,  SNAPF, B4,  o4)  BROWX(5,  SNAPF, B5,  o5)                \
            BROWX(6,  SNAPF, B6,  o6)  BROWX(7,  SNAPF, B7,  o7)                \
            BROWX(8,  SNAPF, B8,  o8)  BROWX(9,  SNAPF, B9,  o9)                \
            BROWX(10, SNAPF, B10, o10) BROWX(11, SNAPF, B11, o11)               \
            BROWX(12, SNAPF, B12, o12) BROWX(13, SNAPF, B13, o13)               \
            BROWX(14, SNAPF, B14, o14) BROWX(15, SNAPF, B15, o15)               \
        }

        const int NPHb = NCHb + NW - 1;
        for (int p = 0; p < NPHb; ++p) {
            const int q = p - (NW - 1 - w);   // wave 7 leads (info flows right->left)
            if (q >= 0 && q < NCHb) {
                const int i0  = istart - 1 - q * CH;
                const int par = q & 1;

                float B0 = NEGF, B1 = NEGF, B2 = NEGF, B3 = NEGF,
                      B4 = NEGF, B5 = NEGF, B6 = NEGF, B7 = NEGF,
                      B8 = NEGF, B9 = NEGF, B10 = NEGF, B11 = NEGF,
                      B12 = NEGF, B13 = NEGF, B14 = NEGF, B15 = NEGF;
                if (w < NW - 1) {   // consume right wave's lane-0 x values
                    const float* vp = &bpub[w][par][0];
                    B0  = vp[0];  B1  = vp[1];  B2  = vp[2];  B3  = vp[3];
                    B4  = vp[4];  B5  = vp[5];  B6  = vp[6];  B7  = vp[7];
                    B8  = vp[8];  B9  = vp[9];  B10 = vp[10]; B11 = vp[11];
                    B12 = vp[12]; B13 = vp[13]; B14 = vp[14]; B15 = vp[15];
                }

                float o0, o1, o2, o3, o4, o5, o6, o7,
                      o8, o9, o10, o11, o12, o13, o14, o15;

                if (q == NCHb - 1) BBODY(true) else BBODY(false)

                if (w > 0 && lane == 0) {     // publish for left wave
                    float* dp = &bpub[w - 1][par][0];
                    dp[0]  = o0;  dp[1]  = o1;  dp[2]  = o2;  dp[3]  = o3;
                    dp[4]  = o4;  dp[5]  = o5;  dp[6]  = o6;  dp[7]  = o7;
                    dp[8]  = o8;  dp[9]  = o9;  dp[10] = o10; dp[11] = o11;
                    dp[12] = o12; dp[13] = o13; dp[14] = o14; dp[15] = o15;
                }
            }
            asm volatile("s_waitcnt lgkmcnt(0)" ::: "memory");
            __builtin_amdgcn_s_barrier();
            asm volatile("" ::: "memory");
        }
#undef BBODY
#undef BROWX
    }
}

// ---------------- Phase 3: LSE join over the cut row ----------------
// ws_final[b] = ln2 * log2 sum_j 2^( alphaB[m,j] + betaB[m,j] )
__global__ __launch_bounds__(512)
void lse_combine(const float* __restrict__ wsA, const float* __restrict__ wsB,
                 float* __restrict__ ws_final)
{
    constexpr float LN2 = 0.69314718055994530942f;
    const int b = blockIdx.x, t = threadIdx.x, lane = t & 63, w = t >> 6;
    __shared__ float red[8];

    const float* A  = wsA + (b << 10);
    const float* Bv = wsB + (b << 10);
    const float v0 = A[2 * t]     + Bv[2 * t];
    const float v1 = A[2 * t + 1] + Bv[2 * t + 1];

    float mx = fmaxf(v0, v1);
#pragma unroll
    for (int off = 1; off < 64; off <<= 1) mx = fmaxf(mx, __shfl_xor(mx, off));
    if (lane == 0) red[w] = mx;
    __syncthreads();
    float gm = red[0];
#pragma unroll
    for (int k = 1; k < 8; ++k) gm = fmaxf(gm, red[k]);

    float s = __builtin_amdgcn_exp2f(v0 - gm) + __builtin_amdgcn_exp2f(v1 - gm);
#pragma unroll
    for (int off = 1; off < 64; off <<= 1) s += __shfl_xor(s, off);
    __syncthreads();
    if (lane == 0) red[w] = s;
    __syncthreads();
    if (t == 0) {
        float tot = red[0];
#pragma unroll
        for (int k = 1; k < 8; ++k) tot += red[k];
        ws_final[b] = (gm + __builtin_amdgcn_logf(tot)) * LN2;
    }
}

// Final scalar: out = -sum(ws_final)/BATCH. Unconditional write.
__global__ void reduce_kernel(const float* __restrict__ ws_final, float* __restrict__ out)
{
    if (threadIdx.x == 0 && blockIdx.x == 0) {
        float s = 0.0f;
        for (int b = 0; b < BATCH; ++b) s += ws_final[b];
        out[0] = -s / (float)BATCH;
    }
}

// ---------------- Fallback (verified R3 kernel) if ws too small ----------------
#define CELL(dst, A, U, E)                                            \
    {                                                                 \
        const float m_ = fmaxf((A), (U));                             \
        const float d_ = (A) - (U);                                   \
        const float p_ = __builtin_amdgcn_exp2f(-fabsf(d_));          \
        const float l_ = __builtin_amdgcn_logf(1.0f + p_);            \
        (dst) = fmaf((E), L2E, m_ + l_);                              \
    }

__global__ __launch_bounds__(256)
void align_dp4(const float* __restrict__ scores,
               const int*   __restrict__ targets,
               const int*   __restrict__ in_len,
               const int*   __restrict__ tg_len,
               float*       __restrict__ ws_final)
{
    constexpr float L2E = 1.44269504088896340736f;
    constexpr float LN2 = 0.69314718055994530942f;

    const int b    = blockIdx.x;
    const int t    = threadIdx.x;
    const int lane = t & 63;
    const int w    = t >> 6;

    __shared__ float elds[4][VOCAB];
    __shared__ float bnd[2][8];

    const int inlen = in_len[b];
    const int tlen  = tg_len[b];

    const gcfp gsc = (gcfp)scores;
    const unsigned base = (unsigned)(b * VOCAB);
    constexpr unsigned ROWW = (unsigned)(BATCH * VOCAB);

    int tok[4];
#pragma unroll
    for (int c = 0; c < 4; ++c) {
        const int col = t * 4 + c;
        tok[c] = targets[b * TARGET_LEN + (col < TARGET_LEN ? col : TARGET_LEN - 1)];
    }

    float prev[4];
#pragma unroll
    for (int c = 0; c < 4; ++c) prev[c] = NEGF;
    if (t == 0) prev[0] = gsc[base + (unsigned)tok[0]] * L2E;

    elds[1][t] = gsc[1u * ROWW + base + (unsigned)t];
    elds[2][t] = gsc[2u * ROWW + base + (unsigned)t];
    if (lane == 63) bnd[0][w] = NEGF;

    float g[4];
    g[3] = gsc[3u * ROWW + base + (unsigned)t];
    g[0] = gsc[4u * ROWW + base + (unsigned)t];
    g[1] = gsc[5u * ROWW + base + (unsigned)t];
    g[2] = gsc[6u * ROWW + base + (unsigned)t];

    const int fth = (tlen - 1) >> 2;
    const int fcc = (tlen - 1) & 3;

#define STEP(K)                                                                    \
    {                                                                              \
        const int i = ib + (K);                                                    \
        if (i < N_FRAMES) {                                                        \
            asm volatile("s_waitcnt lgkmcnt(0)" ::: "memory");                     \
            __builtin_amdgcn_s_barrier();                                          \
            asm volatile("" ::: "memory");                                         \
            const int sl = i & 3;                                                  \
            const float ec0 = elds[sl][tok[0]];                                    \
            const float ec1 = elds[sl][tok[1]];                                    \
            const float ec2 = elds[sl][tok[2]];                                    \
            const float ec3 = elds[sl][tok[3]];                                    \
            const float fromLds = (w > 0) ? bnd[(i - 1) & 1][w - 1] : NEGF;        \
            if (i + 2 < N_FRAMES) elds[(i + 2) & 3][t] = g[((K) + 3) & 3];         \
            if (i + 6 < N_FRAMES)                                                  \
                g[((K) + 3) & 3] = gsc[(unsigned)(i + 6) * ROWW + base + (unsigned)t]; \
            const float sh   = __shfl_up(prev[3], 1);                              \
            const float left = (lane == 0) ? fromLds : sh;                         \
            float cur0, cur1, cur2, cur3;                                          \
            CELL(cur0, left,    prev[0], ec0);                                     \
            CELL(cur1, prev[0], prev[1], ec1);                                     \
            CELL(cur2, prev[1], prev[2], ec2);                                     \
            CELL(cur3, prev[2], prev[3], ec3);                                     \
            if (lane == 63) bnd[i & 1][w] = cur3;                                  \
            if (i == inlen - 1 && t == fth) {                                      \
                const float v = (fcc == 0) ? cur0 : (fcc == 1) ? cur1              \
                              : (fcc == 2) ? cur2 : cur3;                          \
                ws_final[b] = v * LN2;                                             \
            }                                                                      \
            prev[0] = cur0; prev[1] = cur1; prev[2] = cur2; prev[3] = cur3;        \
        }                                                                          \
    }

    for (int ib = 1; ib < N_FRAMES; ib += 4) {
        STEP(0) STEP(1) STEP(2) STEP(3)
    }
#undef STEP
}

extern "C" void kernel_launch(void* const* d_in, const int* in_sizes, int n_in,
                              void* d_out, int out_size, void* d_ws, size_t ws_size,
                              hipStream_t stream)
{
    const float* scores  = (const float*)d_in[0];
    const int*   targets = (const int*)  d_in[1];
    const int*   in_len  = (const int*)  d_in[2];
    const int*   tg_len  = (const int*)  d_in[3];
    float*       out     = (float*)d_out;
    float*       ws_fin  = (float*)d_ws;                     // [0,256): per-batch finals

    const size_t emit_bytes = (size_t)BATCH * N_FRAMES * 1024 * sizeof(__half);
    const size_t wsA_off  = 4096;
    const size_t wsB_off  = wsA_off + (size_t)BATCH * 1024 * sizeof(float);   // +128KB
    const size_t emit_off = wsB_off + (size_t)BATCH * 1024 * sizeof(float);   // +128KB
    const size_t need = emit_off + emit_bytes;

    if (ws_size >= need) {
        __half* emit = (__half*)((char*)d_ws + emit_off);
        float*  wsA  = (float*)((char*)d_ws + wsA_off);
        float*  wsB  = (float*)((char*)d_ws + wsB_off);
        dim3 ggrid(N_FRAMES, BATCH);
        gather_emit<<<ggrid, 256, 0, stream>>>(scores, targets, emit);
        align_dp_fb<<<dim3(BATCH, 2), 512, 0, stream>>>(emit, in_len, tg_len, wsA, wsB);
        lse_combine<<<BATCH, 512, 0, stream>>>(wsA, wsB, ws_fin);
    } else {
        align_dp4<<<BATCH, 256, 0, stream>>>(scores, targets, in_len, tg_len, ws_fin);
    }
    reduce_kernel<<<1, 64, 0, stream>>>(ws_fin, out);
}

// Round 15
// 201.839 us; speedup vs baseline: 6.1894x; 1.0042x over previous
//
#include <hip/hip_runtime.h>
#include <hip/hip_fp16.h>

// Problem constants (from reference)
constexpr int N_FRAMES   = 2000;
constexpr int BATCH      = 32;
constexpr int TARGET_LEN = 1000;
constexpr int VOCAB      = 256;
constexpr int CH         = 32;       // rows per chunk/phase (R14: 16 -> 32)
constexpr int NW         = 8;        // waves per block (2 per SIMD)
#define NEGF (-1e30f)

// addrspace(1) pointers => guaranteed global_load (vmcnt only, never flat).
typedef __attribute__((address_space(1))) const float* gcfp;
typedef __attribute__((address_space(1))) const unsigned* gcu32;

typedef float f32x2 __attribute__((ext_vector_type(2)));

#define H2F(us) __half2float(__ushort_as_half((unsigned short)(us)))

// log2(1+x) on [0,1], degree-5 minimax (validated R9-R13, absmax 0.0),
// Estrin form: dependency depth 4 (vs 6 Horner) to shorten the row chain.
__device__ __forceinline__ f32x2 l21p(f32x2 x) {
    const f32x2 x2 = x * x;
    const f32x2 x4 = x2 * x2;
    f32x2 lo = x * 1.44196727f;
    const f32x2 Bq = x * 0.4176245f  - 0.7096745f;
    const f32x2 Cq = x * 0.0464048f  - 0.1963066f;
    lo = x2 * Bq + lo;
    return x4 * Cq + lo;
}
// c = E + max(A,U) + log2(1+2^-|A-U|)
__device__ __forceinline__ f32x2 lse_e(f32x2 A, f32x2 U, f32x2 E) {
    f32x2 m; m.x = fmaxf(A.x, U.x); m.y = fmaxf(A.y, U.y);
    const f32x2 d = A - U;
    f32x2 x;
    x.x = __builtin_amdgcn_exp2f(-fabsf(d.x));
    x.y = __builtin_amdgcn_exp2f(-fabsf(d.y));
    const f32x2 s = E + m;
    return l21p(x) + s;
}
// c = max(A,U) + log2(1+2^-|A-U|)
__device__ __forceinline__ f32x2 lse_core(f32x2 A, f32x2 U) {
    f32x2 m; m.x = fmaxf(A.x, U.x); m.y = fmaxf(A.y, U.y);
    const f32x2 d = A - U;
    f32x2 x;
    x.x = __builtin_amdgcn_exp2f(-fabsf(d.x));
    x.y = __builtin_amdgcn_exp2f(-fabsf(d.y));
    return l21p(x) + m;
}

// ---------------- Phase 1: massively parallel emit gather ----------------
// emit[b][i][col] = fp16( scores[i,b,tgt[b][min(col,999)]] * log2(e) )
// Rows i >= in_len[b] are never read by the DP (max fwd refill row m+2CH-1
// <= inlen-1 for m>=63) -> skip them (~25% of gather traffic on average).
__global__ __launch_bounds__(256)
void gather_emit(const float* __restrict__ scores,
                 const int*   __restrict__ targets,
                 const int*   __restrict__ in_len,
                 __half*      __restrict__ emit)
{
    constexpr float L2E = 1.44269504088896340736f;
    const int i = blockIdx.x;
    const int b = blockIdx.y;
    if (i >= in_len[b]) return;
    const int t = threadIdx.x;

    const gcfp gsc = (gcfp)scores;
    const unsigned sbase = (unsigned)(i * BATCH * VOCAB + b * VOCAB);

    int tk0, tk1, tk2, tk3;
    if (t < TARGET_LEN / 4) {
        const int4 tk = *(const int4*)&targets[b * TARGET_LEN + 4 * t];
        tk0 = tk.x; tk1 = tk.y; tk2 = tk.z; tk3 = tk.w;
    } else {
        tk0 = tk1 = tk2 = tk3 = targets[b * TARGET_LEN + TARGET_LEN - 1];
    }

    const float e0 = gsc[sbase + (unsigned)tk0] * L2E;
    const float e1 = gsc[sbase + (unsigned)tk1] * L2E;
    const float e2 = gsc[sbase + (unsigned)tk2] * L2E;
    const float e3 = gsc[sbase + (unsigned)tk3] * L2E;

    const unsigned long long h0 = __half_as_ushort(__float2half_rn(e0));
    const unsigned long long h1 = __half_as_ushort(__float2half_rn(e1));
    const unsigned long long h2 = __half_as_ushort(__float2half_rn(e2));
    const unsigned long long h3 = __half_as_ushort(__float2half_rn(e3));

    const unsigned long long u = h0 | (h1 << 16) | (h2 << 32) | (h3 << 48);
    *(unsigned long long*)(emit + (((size_t)(b * N_FRAMES + i)) << 10) + 4 * t) = u;
}

// ---------------- Phase 2: forward+backward halves, one launch ----------------
// grid (BATCH, 2): y==0 forward rows 1..m -> wsA = alpha[m,*];
//                  y==1 backward rows inlen-2..m -> wsB = beta[m,*].
// Verified R12/R13 skeleton: 8 waves x 2 cols/lane, deterministic skewed
// chunks (now CH=32 -> half the barriers), branchless folded bodies, pk cells,
// raw s_barrier + lgkm-only drain per phase (emit-ring vmcnt loads survive).
__global__ __launch_bounds__(512)
void align_dp_fb(const __half* __restrict__ emit,   // [B][N][1024] premult L2E
                 const int*    __restrict__ in_len,
                 const int*    __restrict__ tg_len,
                 float*        __restrict__ wsA,    // [B][1024]
                 float*        __restrict__ wsB)    // [B][1024]
{
    const int b    = blockIdx.x;
    const int t    = threadIdx.x;            // 0..511
    const int lane = t & 63;
    const int w    = t >> 6;                 // 0..7

    __shared__ float bpub[NW - 1][2][CH];

    const int inlen = in_len[b];
    const int m     = (inlen - 1) >> 1;      // cut row (499..999)

    const gcu32 gem = (gcu32)(emit + (((size_t)b * N_FRAMES) << 10));

    if (blockIdx.y == 0) {
        // ================= FORWARD: alpha rows 1..m =================
        const int NCHf = (m + CH - 1) / CH;
        float p0 = NEGF, p1 = NEGF;
        if (t == 0) p0 = H2F(gem[0] & 0xffffu);

        unsigned ring[CH];
#pragma unroll
        for (int r = 0; r < CH; ++r) ring[r] = gem[(unsigned)((1 + r) << 9) + (unsigned)t];

        float shprev = NEGF, carry = NEGF;
        f32x2* wsA2 = (f32x2*)(wsA + (b << 10));

        // all rows/refills in-range (i <= m+31 <= 1030, +32 <= inlen-1): no guards
#define FBODY(SNAPF)                                                            \
        _Pragma("unroll")                                                       \
        for (int r = 0; r < CH; ++r) {                                          \
            const int i = i0 + r;                                               \
            const unsigned u = ring[r];                                         \
            ring[r] = gem[(unsigned)((i + CH) << 9) + (unsigned)t];             \
            f32x2 E; E.x = H2F(u & 0xffffu); E.y = H2F(u >> 16);                \
            f32x2 A; A.x = (lane == 0) ? Bv[r] : shprev; A.y = p0;              \
            f32x2 U; U.x = p0; U.y = p1;                                        \
            const f32x2 c = lse_e(A, U, E);                                     \
            shprev = __shfl_up(c.y, 1);                                         \
            ov[r] = c.y;                                                        \
            if (SNAPF) { if (i == m) wsA2[t] = c; }                             \
            p0 = c.x; p1 = c.y;                                                 \
        }

        const int NPHf = NCHf + NW - 1;
        for (int p = 0; p < NPHf; ++p) {
            const int q = p - w;
            if (q >= 0 && q < NCHf) {
                const int i0  = 1 + q * CH;
                const int par = q & 1;

                float Bv[CH], ov[CH];
#pragma unroll
                for (int r = 0; r < CH; ++r) Bv[r] = NEGF;
                if (w > 0) {
                    const float* vp = &bpub[w - 1][par][0];
                    Bv[0] = carry;
#pragma unroll
                    for (int r = 1; r < CH; ++r) Bv[r] = vp[r - 1];
                    carry = vp[CH - 1];
                }

                if (q == NCHf - 1) FBODY(true) else FBODY(false)

                if (w < NW - 1 && lane == 63) {
                    float* dp = &bpub[w][par][0];
#pragma unroll
                    for (int r = 0; r < CH; ++r) dp[r] = ov[r];
                }
            }
            asm volatile("s_waitcnt lgkmcnt(0)" ::: "memory");
            __builtin_amdgcn_s_barrier();
            asm volatile("" ::: "memory");
        }
#undef FBODY
    } else {
        // ================= BACKWARD: beta rows inlen-2..m =================
        const int tlen   = tg_len[b];
        const int istart = inlen - 1;
        const int NCHb   = (istart - m + CH - 1) / CH;
        const int fth    = (tlen - 1) >> 1;
        const int fcc    = (tlen - 1) & 1;

        float p0 = NEGF, p1 = NEGF;
        if (t == fth) { if (fcc == 0) p0 = 0.0f; else p1 = 0.0f; }

        unsigned ring[CH];
#pragma unroll
        for (int r = 0; r < CH; ++r)
            ring[r] = gem[(unsigned)((istart - r) << 9) + (unsigned)t];

        f32x2* wsB2 = (f32x2*)(wsB + (b << 10));

        // beta[i,j] = LSE(x_j, x_{j+1}), x_j = e[i+1,j] + beta[i+1,j].
        // x at row start -> shfl_down early; publish x.x (lane0). Junk rows
        // below m (tail) compute after snapshot; refills >= m-2CH+2 >= 0.
#define BBODY(SNAPF)                                                            \
        _Pragma("unroll")                                                       \
        for (int r = 0; r < CH; ++r) {                                          \
            const int i = i0 - r;                                               \
            const unsigned u = ring[r];                                         \
            ring[r] = gem[(unsigned)((i + 1 - CH) << 9) + (unsigned)t];         \
            f32x2 E; E.x = H2F(u & 0xffffu); E.y = H2F(u >> 16);                \
            f32x2 P; P.x = p0; P.y = p1;                                        \
            const f32x2 x = E + P;                                              \
            const float sh = __shfl_down(x.x, 1);                               \
            ov[r] = x.x;                                                        \
            const float xR = (lane == 63) ? Bv[r] : sh;                         \
            f32x2 A; A.x = x.x; A.y = x.y;                                      \
            f32x2 U; U.x = x.y; U.y = xR;                                       \
            const f32x2 c = lse_core(A, U);                                     \
            if (SNAPF) { if (i == m) wsB2[t] = c; }                             \
            p0 = c.x; p1 = c.y;                                                 \
        }

        const int NPHb = NCHb + NW - 1;
        for (int p = 0; p < NPHb; ++p) {
            const int q = p - (NW - 1 - w);   // wave 7 leads (info flows right->left)
            if (q >= 0 && q < NCHb) {
                const int i0  = istart - 1 - q * CH;
                const int par = q & 1;

                float Bv[CH], ov[CH];
#pragma unroll
                for (int r = 0; r < CH; ++r) Bv[r] = NEGF;
                if (w < NW - 1) {   // consume right wave's lane-0 x values
                    const float* vp = &bpub[w][par][0];
#pragma unroll
                    for (int r = 0; r < CH; ++r) Bv[r] = vp[r];
                }

                if (q == NCHb - 1) BBODY(true) else BBODY(false)

                if (w > 0 && lane == 0) {     // publish for left wave
                    float* dp = &bpub[w - 1][par][0];
#pragma unroll
                    for (int r = 0; r < CH; ++r) dp[r] = ov[r];
                }
            }
            asm volatile("s_waitcnt lgkmcnt(0)" ::: "memory");
            __builtin_amdgcn_s_barrier();
            asm volatile("" ::: "memory");
        }
#undef BBODY
    }
}

// ---------------- Phase 3: LSE join over the cut row ----------------
// ws_final[b] = ln2 * log2 sum_j 2^( alphaB[m,j] + betaB[m,j] )
__global__ __launch_bounds__(512)
void lse_combine(const float* __restrict__ wsA, const float* __restrict__ wsB,
                 float* __restrict__ ws_final)
{
    constexpr float LN2 = 0.69314718055994530942f;
    const int b = blockIdx.x, t = threadIdx.x, lane = t & 63, w = t >> 6;
    __shared__ float red[8];

    const float* A  = wsA + (b << 10);
    const float* Bv = wsB + (b << 10);
    const float v0 = A[2 * t]     + Bv[2 * t];
    const float v1 = A[2 * t + 1] + Bv[2 * t + 1];

    float mx = fmaxf(v0, v1);
#pragma unroll
    for (int off = 1; off < 64; off <<= 1) mx = fmaxf(mx, __shfl_xor(mx, off));
    if (lane == 0) red[w] = mx;
    __syncthreads();
    float gm = red[0];
#pragma unroll
    for (int k = 1; k < 8; ++k) gm = fmaxf(gm, red[k]);

    float s = __builtin_amdgcn_exp2f(v0 - gm) + __builtin_amdgcn_exp2f(v1 - gm);
#pragma unroll
    for (int off = 1; off < 64; off <<= 1) s += __shfl_xor(s, off);
    __syncthreads();
    if (lane == 0) red[w] = s;
    __syncthreads();
    if (t == 0) {
        float tot = red[0];
#pragma unroll
        for (int k = 1; k < 8; ++k) tot += red[k];
        ws_final[b] = (gm + __builtin_amdgcn_logf(tot)) * LN2;
    }
}

// Final scalar: out = -sum(ws_final)/BATCH. Unconditional write.
__global__ void reduce_kernel(const float* __restrict__ ws_final, float* __restrict__ out)
{
    if (threadIdx.x == 0 && blockIdx.x == 0) {
        float s = 0.0f;
        for (int b = 0; b < BATCH; ++b) s += ws_final[b];
        out[0] = -s / (float)BATCH;
    }
}

// ---------------- Fallback (verified R3 kernel) if ws too small ----------------
#define CELL(dst, A, U, E)                                            \
    {                                                                 \
        const float m_ = fmaxf((A), (U));                             \
        const float d_ = (A) - (U);                                   \
        const float p_ = __builtin_amdgcn_exp2f(-fabsf(d_));          \
        const float l_ = __builtin_amdgcn_logf(1.0f + p_);            \
        (dst) = fmaf((E), L2E, m_ + l_);                              \
    }

__global__ __launch_bounds__(256)
void align_dp4(const float* __restrict__ scores,
               const int*   __restrict__ targets,
               const int*   __restrict__ in_len,
               const int*   __restrict__ tg_len,
               float*       __restrict__ ws_final)
{
    constexpr float L2E = 1.44269504088896340736f;
    constexpr float LN2 = 0.69314718055994530942f;

    const int b    = blockIdx.x;
    const int t    = threadIdx.x;
    const int lane = t & 63;
    const int w    = t >> 6;

    __shared__ float elds[4][VOCAB];
    __shared__ float bnd[2][8];

    const int inlen = in_len[b];
    const int tlen  = tg_len[b];

    const gcfp gsc = (gcfp)scores;
    const unsigned base = (unsigned)(b * VOCAB);
    constexpr unsigned ROWW = (unsigned)(BATCH * VOCAB);

    int tok[4];
#pragma unroll
    for (int c = 0; c < 4; ++c) {
        const int col = t * 4 + c;
        tok[c] = targets[b * TARGET_LEN + (col < TARGET_LEN ? col : TARGET_LEN - 1)];
    }

    float prev[4];
#pragma unroll
    for (int c = 0; c < 4; ++c) prev[c] = NEGF;
    if (t == 0) prev[0] = gsc[base + (unsigned)tok[0]] * L2E;

    elds[1][t] = gsc[1u * ROWW + base + (unsigned)t];
    elds[2][t] = gsc[2u * ROWW + base + (unsigned)t];
    if (lane == 63) bnd[0][w] = NEGF;

    float g[4];
    g[3] = gsc[3u * ROWW + base + (unsigned)t];
    g[0] = gsc[4u * ROWW + base + (unsigned)t];
    g[1] = gsc[5u * ROWW + base + (unsigned)t];
    g[2] = gsc[6u * ROWW + base + (unsigned)t];

    const int fth = (tlen - 1) >> 2;
    const int fcc = (tlen - 1) & 3;

#define STEP(K)                                                                    \
    {                                                                              \
        const int i = ib + (K);                                                    \
        if (i < N_FRAMES) {                                                        \
            asm volatile("s_waitcnt lgkmcnt(0)" ::: "memory");                     \
            __builtin_amdgcn_s_barrier();                                          \
            asm volatile("" ::: "memory");                                         \
            const int sl = i & 3;                                                  \
            const float ec0 = elds[sl][tok[0]];                                    \
            const float ec1 = elds[sl][tok[1]];                                    \
            const float ec2 = elds[sl][tok[2]];                                    \
            const float ec3 = elds[sl][tok[3]];                                    \
            const float fromLds = (w > 0) ? bnd[(i - 1) & 1][w - 1] : NEGF;        \
            if (i + 2 < N_FRAMES) elds[(i + 2) & 3][t] = g[((K) + 3) & 3];         \
            if (i + 6 < N_FRAMES)                                                  \
                g[((K) + 3) & 3] = gsc[(unsigned)(i + 6) * ROWW + base + (unsigned)t]; \
            const float sh   = __shfl_up(prev[3], 1);                              \
            const float left = (lane == 0) ? fromLds : sh;                         \
            float cur0, cur1, cur2, cur3;                                          \
            CELL(cur0, left,    prev[0], ec0);                                     \
            CELL(cur1, prev[0], prev[1], ec1);                                     \
            CELL(cur2, prev[1], prev[2], ec2);                                     \
            CELL(cur3, prev[2], prev[3], ec3);                                     \
            if (lane == 63) bnd[i & 1][w] = cur3;                                  \
            if (i == inlen - 1 && t == fth) {                                      \
                const float v = (fcc == 0) ? cur0 : (fcc == 1) ? cur1              \
                              : (fcc == 2) ? cur2 : cur3;                          \
                ws_final[b] = v * LN2;                                             \
            }                                                                      \
            prev[0] = cur0; prev[1] = cur1; prev[2] = cur2; prev[3] = cur3;        \
        }                                                                          \
    }

    for (int ib = 1; ib < N_FRAMES; ib += 4) {
        STEP(0) STEP(1) STEP(2) STEP(3)
    }
#undef STEP
}

extern "C" void kernel_launch(void* const* d_in, const int* in_sizes, int n_in,
                              void* d_out, int out_size, void* d_ws, size_t ws_size,
                              hipStream_t stream)
{
    const float* scores  = (const float*)d_in[0];
    const int*   targets = (const int*)  d_in[1];
    const int*   in_len  = (const int*)  d_in[2];
    const int*   tg_len  = (const int*)  d_in[3];
    float*       out     = (float*)d_out;
    float*       ws_fin  = (float*)d_ws;                     // [0,256): per-batch finals

    const size_t emit_bytes = (size_t)BATCH * N_FRAMES * 1024 * sizeof(__half);
    const size_t wsA_off  = 4096;
    const size_t wsB_off  = wsA_off + (size_t)BATCH * 1024 * sizeof(float);   // +128KB
    const size_t emit_off = wsB_off + (size_t)BATCH * 1024 * sizeof(float);   // +128KB
    const size_t need = emit_off + emit_bytes;

    if (ws_size >= need) {
        __half* emit = (__half*)((char*)d_ws + emit_off);
        float*  wsA  = (float*)((char*)d_ws + wsA_off);
        float*  wsB  = (float*)((char*)d_ws + wsB_off);
        dim3 ggrid(N_FRAMES, BATCH);
        gather_emit<<<ggrid, 256, 0, stream>>>(scores, targets, in_len, emit);
        align_dp_fb<<<dim3(BATCH, 2), 512, 0, stream>>>(emit, in_len, tg_len, wsA, wsB);
        lse_combine<<<BATCH, 512, 0, stream>>>(wsA, wsB, ws_fin);
    } else {
        align_dp4<<<BATCH, 256, 0, stream>>>(scores, targets, in_len, tg_len, ws_fin);
    }
    reduce_kernel<<<1, 64, 0, stream>>>(ws_fin, out);
}

// Round 17
// 187.388 us; speedup vs baseline: 6.6667x; 1.0771x over previous
//
#include <hip/hip_runtime.h>
#include <hip/hip_fp16.h>

// Problem constants (from reference)
constexpr int N_FRAMES   = 2000;
constexpr int BATCH      = 32;
constexpr int TARGET_LEN = 1000;
constexpr int VOCAB      = 256;
constexpr int CH         = 16;       // rows per chunk/phase (R13-proven)
constexpr int NW         = 8;        // waves per block (2 per SIMD)
#define NEGF (-1e30f)

// addrspace(1) pointers => guaranteed global_load (vmcnt only, never flat).
typedef __attribute__((address_space(1))) const float* gcfp;
typedef __attribute__((address_space(1))) const unsigned* gcu32;

typedef float f32x2 __attribute__((ext_vector_type(2)));

#define H2F(us) __half2float(__ushort_as_half((unsigned short)(us)))

// Cross-lane shift-by-1 via DPP (pure VALU, ~2cy, NO LDS pipe / lgkmcnt).
// AMD DPP: data flows toward HIGHER lanes under shr (scan idiom uses row_shr).
//   wf_sr1 (0x138): lane n <- lane n-1  == shfl_up(x,1)
//   wf_sl1 (0x130): lane n <- lane n+1  == shfl_down(x,1)
// (R15 ERRATA: had these swapped -> absmax 7372. Fixed.)
// Invalid boundary lane gets 'old' (0); both call sites overwrite it via select.
#if __has_builtin(__builtin_amdgcn_update_dpp)
__device__ __forceinline__ float lane_up1(float x) {
    return __int_as_float(__builtin_amdgcn_update_dpp(
        0, __float_as_int(x), 0x138, 0xf, 0xf, false));
}
__device__ __forceinline__ float lane_dn1(float x) {
    return __int_as_float(__builtin_amdgcn_update_dpp(
        0, __float_as_int(x), 0x130, 0xf, 0xf, false));
}
#else
__device__ __forceinline__ float lane_up1(float x) { return __shfl_up(x, 1); }
__device__ __forceinline__ float lane_dn1(float x) { return __shfl_down(x, 1); }
#endif

// log2(1+x) on [0,1], degree-5 minimax (validated R9-R14, absmax 0.0),
// Estrin form: dependency depth 4.
__device__ __forceinline__ f32x2 l21p(f32x2 x) {
    const f32x2 x2 = x * x;
    const f32x2 x4 = x2 * x2;
    f32x2 lo = x * 1.44196727f;
    const f32x2 Bq = x * 0.4176245f  - 0.7096745f;
    const f32x2 Cq = x * 0.0464048f  - 0.1963066f;
    lo = x2 * Bq + lo;
    return x4 * Cq + lo;
}
// c = E + max(A,U) + log2(1+2^-|A-U|)
__device__ __forceinline__ f32x2 lse_e(f32x2 A, f32x2 U, f32x2 E) {
    f32x2 m; m.x = fmaxf(A.x, U.x); m.y = fmaxf(A.y, U.y);
    const f32x2 d = A - U;
    f32x2 x;
    x.x = __builtin_amdgcn_exp2f(-fabsf(d.x));
    x.y = __builtin_amdgcn_exp2f(-fabsf(d.y));
    const f32x2 s = E + m;
    return l21p(x) + s;
}
// c = max(A,U) + log2(1+2^-|A-U|)
__device__ __forceinline__ f32x2 lse_core(f32x2 A, f32x2 U) {
    f32x2 m; m.x = fmaxf(A.x, U.x); m.y = fmaxf(A.y, U.y);
    const f32x2 d = A - U;
    f32x2 x;
    x.x = __builtin_amdgcn_exp2f(-fabsf(d.x));
    x.y = __builtin_amdgcn_exp2f(-fabsf(d.y));
    return l21p(x) + m;
}

// ---------------- Phase 1: massively parallel emit gather ----------------
// emit[b][i][col] = fp16( scores[i,b,tgt[b][min(col,999)]] * log2(e) )
// Rows i >= in_len[b] are never read by the DP -> skip (~25% traffic).
__global__ __launch_bounds__(256)
void gather_emit(const float* __restrict__ scores,
                 const int*   __restrict__ targets,
                 const int*   __restrict__ in_len,
                 __half*      __restrict__ emit)
{
    constexpr float L2E = 1.44269504088896340736f;
    const int i = blockIdx.x;
    const int b = blockIdx.y;
    if (i >= in_len[b]) return;
    const int t = threadIdx.x;

    const gcfp gsc = (gcfp)scores;
    const unsigned sbase = (unsigned)(i * BATCH * VOCAB + b * VOCAB);

    int tk0, tk1, tk2, tk3;
    if (t < TARGET_LEN / 4) {
        const int4 tk = *(const int4*)&targets[b * TARGET_LEN + 4 * t];
        tk0 = tk.x; tk1 = tk.y; tk2 = tk.z; tk3 = tk.w;
    } else {
        tk0 = tk1 = tk2 = tk3 = targets[b * TARGET_LEN + TARGET_LEN - 1];
    }

    const float e0 = gsc[sbase + (unsigned)tk0] * L2E;
    const float e1 = gsc[sbase + (unsigned)tk1] * L2E;
    const float e2 = gsc[sbase + (unsigned)tk2] * L2E;
    const float e3 = gsc[sbase + (unsigned)tk3] * L2E;

    const unsigned long long h0 = __half_as_ushort(__float2half_rn(e0));
    const unsigned long long h1 = __half_as_ushort(__float2half_rn(e1));
    const unsigned long long h2 = __half_as_ushort(__float2half_rn(e2));
    const unsigned long long h3 = __half_as_ushort(__float2half_rn(e3));

    const unsigned long long u = h0 | (h1 << 16) | (h2 << 32) | (h3 << 48);
    *(unsigned long long*)(emit + (((size_t)(b * N_FRAMES + i)) << 10) + 4 * t) = u;
}

// ---------------- Phase 2: forward+backward halves, one launch ----------------
// grid (BATCH, 2): y==0 forward rows 1..m -> wsA = alpha[m,*];
//                  y==1 backward rows inlen-2..m -> wsB = beta[m,*].
// R13-verified skeleton (CH=16): 8 waves x 2 cols/lane, deterministic skewed
// chunks, branchless folded bodies, pk cells, raw s_barrier + lgkm-only drain
// per phase. Cross-lane neighbor via DPP (no per-row LDS ops at all).
__global__ __launch_bounds__(512)
void align_dp_fb(const __half* __restrict__ emit,   // [B][N][1024] premult L2E
                 const int*    __restrict__ in_len,
                 const int*    __restrict__ tg_len,
                 float*        __restrict__ wsA,    // [B][1024]
                 float*        __restrict__ wsB)    // [B][1024]
{
    const int b    = blockIdx.x;
    const int t    = threadIdx.x;            // 0..511
    const int lane = t & 63;
    const int w    = t >> 6;                 // 0..7

    __shared__ float bpub[NW - 1][2][CH];

    const int inlen = in_len[b];
    const int m     = (inlen - 1) >> 1;      // cut row (499..999)

    const gcu32 gem = (gcu32)(emit + (((size_t)b * N_FRAMES) << 10));

    if (blockIdx.y == 0) {
        // ================= FORWARD: alpha rows 1..m =================
        const int NCHf = (m + CH - 1) / CH;
        float p0 = NEGF, p1 = NEGF;
        if (t == 0) p0 = H2F(gem[0] & 0xffffu);

        unsigned ring[CH];
#pragma unroll
        for (int r = 0; r < CH; ++r) ring[r] = gem[(unsigned)((1 + r) << 9) + (unsigned)t];

        float shprev = NEGF, carry = NEGF;
        f32x2* wsA2 = (f32x2*)(wsA + (b << 10));

        // all rows/refills in-range (i <= m+15, +16 <= inlen-1): no guards
#define FROWX(r, SNAPF, Bv, Ov)                                                 \
        {                                                                       \
            const int i = i0 + (r);                                             \
            const unsigned u = ring[r];                                         \
            ring[r] = gem[(unsigned)((i + CH) << 9) + (unsigned)t];             \
            f32x2 E; E.x = H2F(u & 0xffffu); E.y = H2F(u >> 16);                \
            f32x2 A; A.x = (lane == 0) ? (Bv) : shprev; A.y = p0;               \
            f32x2 U; U.x = p0; U.y = p1;                                        \
            const f32x2 c = lse_e(A, U, E);                                     \
            shprev = lane_up1(c.y);                                             \
            (Ov) = c.y;                                                         \
            if (SNAPF) { if (i == m) wsA2[t] = c; }                             \
            p0 = c.x; p1 = c.y;                                                 \
        }

#define FBODY(SNAPF)                                                            \
        {                                                                       \
            FROWX(0,  SNAPF, B0,  o0)  FROWX(1,  SNAPF, B1,  o1)                \
            FROWX(2,  SNAPF, B2,  o2)  FROWX(3,  SNAPF, B3,  o3)                \
            FROWX(4,  SNAPF, B4,  o4)  FROWX(5,  SNAPF, B5,  o5)                \
            FROWX(6,  SNAPF, B6,  o6)  FROWX(7,  SNAPF, B7,  o7)                \
            FROWX(8,  SNAPF, B8,  o8)  FROWX(9,  SNAPF, B9,  o9)                \
            FROWX(10, SNAPF, B10, o10) FROWX(11, SNAPF, B11, o11)               \
            FROWX(12, SNAPF, B12, o12) FROWX(13, SNAPF, B13, o13)               \
            FROWX(14, SNAPF, B14, o14) FROWX(15, SNAPF, B15, o15)               \
        }

        const int NPHf = NCHf + NW - 1;
        for (int p = 0; p < NPHf; ++p) {
            const int q = p - w;
            if (q >= 0 && q < NCHf) {
                const int i0  = 1 + q * CH;
                const int par = q & 1;

                float B0 = NEGF, B1 = NEGF, B2 = NEGF, B3 = NEGF,
                      B4 = NEGF, B5 = NEGF, B6 = NEGF, B7 = NEGF,
                      B8 = NEGF, B9 = NEGF, B10 = NEGF, B11 = NEGF,
                      B12 = NEGF, B13 = NEGF, B14 = NEGF, B15 = NEGF;
                if (w > 0) {
                    const float* vp = &bpub[w - 1][par][0];
                    B0 = carry;
                    B1  = vp[0];  B2  = vp[1];  B3  = vp[2];  B4  = vp[3];
                    B5  = vp[4];  B6  = vp[5];  B7  = vp[6];  B8  = vp[7];
                    B9  = vp[8];  B10 = vp[9];  B11 = vp[10]; B12 = vp[11];
                    B13 = vp[12]; B14 = vp[13]; B15 = vp[14];
                    carry = vp[15];
                }

                float o0, o1, o2, o3, o4, o5, o6, o7,
                      o8, o9, o10, o11, o12, o13, o14, o15;

                if (q == NCHf - 1) FBODY(true) else FBODY(false)

                if (w < NW - 1 && lane == 63) {
                    float* dp = &bpub[w][par][0];
                    dp[0]  = o0;  dp[1]  = o1;  dp[2]  = o2;  dp[3]  = o3;
                    dp[4]  = o4;  dp[5]  = o5;  dp[6]  = o6;  dp[7]  = o7;
                    dp[8]  = o8;  dp[9]  = o9;  dp[10] = o10; dp[11] = o11;
                    dp[12] = o12; dp[13] = o13; dp[14] = o14; dp[15] = o15;
                }
            }
            asm volatile("s_waitcnt lgkmcnt(0)" ::: "memory");
            __builtin_amdgcn_s_barrier();
            asm volatile("" ::: "memory");
        }
#undef FBODY
#undef FROWX
    } else {
        // ================= BACKWARD: beta rows inlen-2..m =================
        const int tlen   = tg_len[b];
        const int istart = inlen - 1;
        const int NCHb   = (istart - m + CH - 1) / CH;
        const int fth    = (tlen - 1) >> 1;
        const int fcc    = (tlen - 1) & 1;

        float p0 = NEGF, p1 = NEGF;
        if (t == fth) { if (fcc == 0) p0 = 0.0f; else p1 = 0.0f; }

        unsigned ring[CH];
#pragma unroll
        for (int r = 0; r < CH; ++r)
            ring[r] = gem[(unsigned)((istart - r) << 9) + (unsigned)t];

        f32x2* wsB2 = (f32x2*)(wsB + (b << 10));

        // beta[i,j] = LSE(x_j, x_{j+1}), x_j = e[i+1,j] + beta[i+1,j].
        // x at row start -> DPP shift down; publish x.x (lane0). Junk rows
        // below m (tail) compute after snapshot; refills >= m-2CH+2 >= 0.
#define BROWX(r, SNAPF, Bv, Ov)                                                 \
        {                                                                       \
            const int i = i0 - (r);                                             \
            const unsigned u = ring[r];                                         \
            ring[r] = gem[(unsigned)((i + 1 - CH) << 9) + (unsigned)t];         \
            f32x2 E; E.x = H2F(u & 0xffffu); E.y = H2F(u >> 16);                \
            f32x2 P; P.x = p0; P.y = p1;                                        \
            const f32x2 x = E + P;                                              \
            const float sh = lane_dn1(x.x);                                     \
            (Ov) = x.x;                                                         \
            const float xR = (lane == 63) ? (Bv) : sh;                          \
            f32x2 A; A.x = x.x; A.y = x.y;                                      \
            f32x2 U; U.x = x.y; U.y = xR;                                       \
            const f32x2 c = lse_core(A, U);                                     \
            if (SNAPF) { if (i == m) wsB2[t] = c; }                             \
            p0 = c.x; p1 = c.y;                                                 \
        }

#define BBODY(SNAPF)                                                            \
        {                                                                       \
            BROWX(0,  SNAPF, B0,  o0)  BROWX(1,  SNAPF, B1,  o1)                \
            BROWX(2,  SNAPF, B2,  o2)  BROWX(3,  SNAPF, B3,  o3)                \
            BROWX(4,  SNAPF, B4,  o4)  BROWX(5,  SNAPF, B5,  o5)                \
            BROWX(6,  SNAPF, B6,  o6)  BROWX(7,  SNAPF, B7,  o7)                \
            BROWX(8,  SNAPF, B8,  o8)  BROWX(9,  SNAPF, B9,  o9)                \
            BROWX(10, SNAPF, B10, o10) BROWX(11, SNAPF, B11, o11)               \
            BROWX(12, SNAPF, B12, o12) BROWX(13, SNAPF, B13, o13)               \
            BROWX(14, SNAPF, B14, o14) BROWX(15, SNAPF, B15, o15)               \
        }

        const int NPHb = NCHb + NW - 1;
        for (int p = 0; p < NPHb; ++p) {
            const int q = p - (NW - 1 - w);   // wave 7 leads (info flows right->left)
            if (q >= 0 && q < NCHb) {
                const int i0  = istart - 1 - q * CH;
                const int par = q & 1;

                float B0 = NEGF, B1 = NEGF, B2 = NEGF, B3 = NEGF,
                      B4 = NEGF, B5 = NEGF, B6 = NEGF, B7 = NEGF,
                      B8 = NEGF, B9 = NEGF, B10 = NEGF, B11 = NEGF,
                      B12 = NEGF, B13 = NEGF, B14 = NEGF, B15 = NEGF;
                if (w < NW - 1) {   // consume right wave's lane-0 x values
                    const float* vp = &bpub[w][par][0];
                    B0  = vp[0];  B1  = vp[1];  B2  = vp[2];  B3  = vp[3];
                    B4  = vp[4];  B5  = vp[5];  B6  = vp[6];  B7  = vp[7];
                    B8  = vp[8];  B9  = vp[9];  B10 = vp[10]; B11 = vp[11];
                    B12 = vp[12]; B13 = vp[13]; B14 = vp[14]; B15 = vp[15];
                }

                float o0, o1, o2, o3, o4, o5, o6, o7,
                      o8, o9, o10, o11, o12, o13, o14, o15;

                if (q == NCHb - 1) BBODY(true) else BBODY(false)

                if (w > 0 && lane == 0) {     // publish for left wave
                    float* dp = &bpub[w - 1][par][0];
                    dp[0]  = o0;  dp[1]  = o1;  dp[2]  = o2;  dp[3]  = o3;
                    dp[4]  = o4;  dp[5]  = o5;  dp[6]  = o6;  dp[7]  = o7;
                    dp[8]  = o8;  dp[9]  = o9;  dp[10] = o10; dp[11] = o11;
                    dp[12] = o12; dp[13] = o13; dp[14] = o14; dp[15] = o15;
                }
            }
            asm volatile("s_waitcnt lgkmcnt(0)" ::: "memory");
            __builtin_amdgcn_s_barrier();
            asm volatile("" ::: "memory");
        }
#undef BBODY
#undef BROWX
    }
}

// ---------------- Phase 3: LSE join over the cut row ----------------
// ws_final[b] = ln2 * log2 sum_j 2^( alphaB[m,j] + betaB[m,j] )
__global__ __launch_bounds__(512)
void lse_combine(const float* __restrict__ wsA, const float* __restrict__ wsB,
                 float* __restrict__ ws_final)
{
    constexpr float LN2 = 0.69314718055994530942f;
    const int b = blockIdx.x, t = threadIdx.x, lane = t & 63, w = t >> 6;
    __shared__ float red[8];

    const float* A  = wsA + (b << 10);
    const float* Bv = wsB + (b << 10);
    const float v0 = A[2 * t]     + Bv[2 * t];
    const float v1 = A[2 * t + 1] + Bv[2 * t + 1];

    float mx = fmaxf(v0, v1);
#pragma unroll
    for (int off = 1; off < 64; off <<= 1) mx = fmaxf(mx, __shfl_xor(mx, off));
    if (lane == 0) red[w] = mx;
    __syncthreads();
    float gm = red[0];
#pragma unroll
    for (int k = 1; k < 8; ++k) gm = fmaxf(gm, red[k]);

    float s = __builtin_amdgcn_exp2f(v0 - gm) + __builtin_amdgcn_exp2f(v1 - gm);
#pragma unroll
    for (int off = 1; off < 64; off <<= 1) s += __shfl_xor(s, off);
    __syncthreads();
    if (lane == 0) red[w] = s;
    __syncthreads();
    if (t == 0) {
        float tot = red[0];
#pragma unroll
        for (int k = 1; k < 8; ++k) tot += red[k];
        ws_final[b] = (gm + __builtin_amdgcn_logf(tot)) * LN2;
    }
}

// Final scalar: out = -sum(ws_final)/BATCH. Unconditional write.
__global__ void reduce_kernel(const float* __restrict__ ws_final, float* __restrict__ out)
{
    if (threadIdx.x == 0 && blockIdx.x == 0) {
        float s = 0.0f;
        for (int b = 0; b < BATCH; ++b) s += ws_final[b];
        out[0] = -s / (float)BATCH;
    }
}

// ---------------- Fallback (verified R3 kernel) if ws too small ----------------
#define CELL(dst, A, U, E)                                            \
    {                                                                 \
        const float m_ = fmaxf((A), (U));                             \
        const float d_ = (A) - (U);                                   \
        const float p_ = __builtin_amdgcn_exp2f(-fabsf(d_));          \
        const float l_ = __builtin_amdgcn_logf(1.0f + p_);            \
        (dst) = fmaf((E), L2E, m_ + l_);                              \
    }

__global__ __launch_bounds__(256)
void align_dp4(const float* __restrict__ scores,
               const int*   __restrict__ targets,
               const int*   __restrict__ in_len,
               const int*   __restrict__ tg_len,
               float*       __restrict__ ws_final)
{
    constexpr float L2E = 1.44269504088896340736f;
    constexpr float LN2 = 0.69314718055994530942f;

    const int b    = blockIdx.x;
    const int t    = threadIdx.x;
    const int lane = t & 63;
    const int w    = t >> 6;

    __shared__ float elds[4][VOCAB];
    __shared__ float bnd[2][8];

    const int inlen = in_len[b];
    const int tlen  = tg_len[b];

    const gcfp gsc = (gcfp)scores;
    const unsigned base = (unsigned)(b * VOCAB);
    constexpr unsigned ROWW = (unsigned)(BATCH * VOCAB);

    int tok[4];
#pragma unroll
    for (int c = 0; c < 4; ++c) {
        const int col = t * 4 + c;
        tok[c] = targets[b * TARGET_LEN + (col < TARGET_LEN ? col : TARGET_LEN - 1)];
    }

    float prev[4];
#pragma unroll
    for (int c = 0; c < 4; ++c) prev[c] = NEGF;
    if (t == 0) prev[0] = gsc[base + (unsigned)tok[0]] * L2E;

    elds[1][t] = gsc[1u * ROWW + base + (unsigned)t];
    elds[2][t] = gsc[2u * ROWW + base + (unsigned)t];
    if (lane == 63) bnd[0][w] = NEGF;

    float g[4];
    g[3] = gsc[3u * ROWW + base + (unsigned)t];
    g[0] = gsc[4u * ROWW + base + (unsigned)t];
    g[1] = gsc[5u * ROWW + base + (unsigned)t];
    g[2] = gsc[6u * ROWW + base + (unsigned)t];

    const int fth = (tlen - 1) >> 2;
    const int fcc = (tlen - 1) & 3;

#define STEP(K)                                                                    \
    {                                                                              \
        const int i = ib + (K);                                                    \
        if (i < N_FRAMES) {                                                        \
            asm volatile("s_waitcnt lgkmcnt(0)" ::: "memory");                     \
            __builtin_amdgcn_s_barrier();                                          \
            asm volatile("" ::: "memory");                                         \
            const int sl = i & 3;                                                  \
            const float ec0 = elds[sl][tok[0]];                                    \
            const float ec1 = elds[sl][tok[1]];                                    \
            const float ec2 = elds[sl][tok[2]];                                    \
            const float ec3 = elds[sl][tok[3]];                                    \
            const float fromLds = (w > 0) ? bnd[(i - 1) & 1][w - 1] : NEGF;        \
            if (i + 2 < N_FRAMES) elds[(i + 2) & 3][t] = g[((K) + 3) & 3];         \
            if (i + 6 < N_FRAMES)                                                  \
                g[((K) + 3) & 3] = gsc[(unsigned)(i + 6) * ROWW + base + (unsigned)t]; \
            const float sh   = __shfl_up(prev[3], 1);                              \
            const float left = (lane == 0) ? fromLds : sh;                         \
            float cur0, cur1, cur2, cur3;                                          \
            CELL(cur0, left,    prev[0], ec0);                                     \
            CELL(cur1, prev[0], prev[1], ec1);                                     \
            CELL(cur2, prev[1], prev[2], ec2);                                     \
            CELL(cur3, prev[2], prev[3], ec3);                                     \
            if (lane == 63) bnd[i & 1][w] = cur3;                                  \
            if (i == inlen - 1 && t == fth) {                                      \
                const float v = (fcc == 0) ? cur0 : (fcc == 1) ? cur1              \
                              : (fcc == 2) ? cur2 : cur3;                          \
                ws_final[b] = v * LN2;                                             \
            }                                                                      \
            prev[0] = cur0; prev[1] = cur1; prev[2] = cur2; prev[3] = cur3;        \
        }                                                                          \
    }

    for (int ib = 1; ib < N_FRAMES; ib += 4) {
        STEP(0) STEP(1) STEP(2) STEP(3)
    }
#undef STEP
}

extern "C" void kernel_launch(void* const* d_in, const int* in_sizes, int n_in,
                              void* d_out, int out_size, void* d_ws, size_t ws_size,
                              hipStream_t stream)
{
    const float* scores  = (const float*)d_in[0];
    const int*   targets = (const int*)  d_in[1];
    const int*   in_len  = (const int*)  d_in[2];
    const int*   tg_len  = (const int*)  d_in[3];
    float*       out     = (float*)d_out;
    float*       ws_fin  = (float*)d_ws;                     // [0,256): per-batch finals

    const size_t emit_bytes = (size_t)BATCH * N_FRAMES * 1024 * sizeof(__half);
    const size_t wsA_off  = 4096;
    const size_t wsB_off  = wsA_off + (size_t)BATCH * 1024 * sizeof(float);   // +128KB
    const size_t emit_off = wsB_off + (size_t)BATCH * 1024 * sizeof(float);   // +128KB
    const size_t need = emit_off + emit_bytes;

    if (ws_size >= need) {
        __half* emit = (__half*)((char*)d_ws + emit_off);
        float*  wsA  = (float*)((char*)d_ws + wsA_off);
        float*  wsB  = (float*)((char*)d_ws + wsB_off);
        dim3 ggrid(N_FRAMES, BATCH);
        gather_emit<<<ggrid, 256, 0, stream>>>(scores, targets, in_len, emit);
        align_dp_fb<<<dim3(BATCH, 2), 512, 0, stream>>>(emit, in_len, tg_len, wsA, wsB);
        lse_combine<<<BATCH, 512, 0, stream>>>(wsA, wsB, ws_fin);
    } else {
        align_dp4<<<BATCH, 256, 0, stream>>>(scores, targets, in_len, tg_len, ws_fin);
    }
    reduce_kernel<<<1, 64, 0, stream>>>(ws_fin, out);
}